// Round 8
// baseline (652.167 us; speedup 1.0000x reference)
//
#include <hip/hip_runtime.h>

#define N_NODES 50000
#define N_EDGES 400000
#define DH 128
#define N_GRAPHS 256

#define SCAN_CHUNK 512
#define N_CHUNKS ((N_NODES + SCAN_CHUNK - 1) / SCAN_CHUNK)   // 98
#define BN_BLOCKS 512

typedef __bf16 bf16x8 __attribute__((ext_vector_type(8)));
typedef float f32x4 __attribute__((ext_vector_type(4)));
typedef _Float16 f16x4 __attribute__((ext_vector_type(4)));

#define DEV __device__ __forceinline__

DEV unsigned short f2bf(float f) {
  union { float f; unsigned int i; } v; v.f = f;
  unsigned int x = v.i;
  unsigned int r = (x + 0x7fffu + ((x >> 16) & 1u)) >> 16;
  return (unsigned short)r;
}

// ---- weight repack into MFMA B-fragment order ------------------------------
struct WPtrs { const float* w[12]; };

__global__ void repack_kernel(WPtrs wp, unsigned short* __restrict__ WB) {
  int mat = blockIdx.y;
  int m = blockIdx.x * 256 + threadIdx.x;   // 0..16383
  int j = m & 7;
  int lane = (m >> 3) & 63;
  int ct = (m >> 9) & 7;
  int kk = m >> 12;
  int i = kk * 32 + (lane >> 4) * 8 + j;
  int o = ct * 16 + (lane & 15);
  WB[mat * 16384 + m] = f2bf(wp.w[mat][i * 128 + o]);
}

// ---------------- fp32 -> bf16 convert (layer-0 x) ---------------------------
__global__ void f32_to_bf16(const float* __restrict__ in, unsigned short* __restrict__ out,
                            int total4) {
  int i = blockIdx.x * 256 + threadIdx.x;
  if (i >= total4) return;
  float4 v = *reinterpret_cast<const float4*>(in + i * 4);
  ushort4 o;
  o.x = f2bf(v.x); o.y = f2bf(v.y); o.z = f2bf(v.z); o.w = f2bf(v.w);
  *reinterpret_cast<ushort4*>(out + i * 4) = o;
}

// ---------------- CSR build --------------------------------------------------
__global__ void deg_count(const int* __restrict__ ei, int* __restrict__ deg, int E) {
  int e = blockIdx.x * 256 + threadIdx.x;
  if (e < E) atomicAdd(&deg[ei[E + e]], 1);
}

__global__ __launch_bounds__(256) void scan_sum(const int* __restrict__ deg,
                                                int* __restrict__ partials, int N) {
  __shared__ int red[256];
  int b = blockIdx.x, t = threadIdx.x;
  int base = b * SCAN_CHUNK + t * 2;
  int s = 0;
  if (base + 1 < N) { int2 v = *reinterpret_cast<const int2*>(deg + base); s = v.x + v.y; }
  else if (base < N) s = deg[base];
  red[t] = s;
  __syncthreads();
  for (int off = 128; off; off >>= 1) {
    if (t < off) red[t] += red[t + off];
    __syncthreads();
  }
  if (t == 0) partials[b] = red[0];
}

__global__ __launch_bounds__(128) void scan_partials(int* __restrict__ partials) {
  __shared__ int s[128];
  int t = threadIdx.x;
  int v = (t < N_CHUNKS) ? partials[t] : 0;
  s[t] = v;
  __syncthreads();
  for (int off = 1; off < 128; off <<= 1) {
    int o = (t >= off) ? s[t - off] : 0;
    __syncthreads();
    s[t] += o;
    __syncthreads();
  }
  if (t < N_CHUNKS) partials[t] = s[t] - v;   // exclusive
}

__global__ __launch_bounds__(256) void scan_apply(const int* __restrict__ deg,
                                                  const int* __restrict__ partials,
                                                  int* __restrict__ rowptr,
                                                  int* __restrict__ cursor, int N, int E) {
  __shared__ int s[256];
  int b = blockIdx.x, t = threadIdx.x;
  int base = b * SCAN_CHUNK + t * 2;
  int d0 = 0, d1 = 0;
  if (base + 1 < N) { int2 v = *reinterpret_cast<const int2*>(deg + base); d0 = v.x; d1 = v.y; }
  else if (base < N) d0 = deg[base];
  int local = d0 + d1;
  s[t] = local;
  __syncthreads();
  for (int off = 1; off < 256; off <<= 1) {
    int o = (t >= off) ? s[t - off] : 0;
    __syncthreads();
    s[t] += o;
    __syncthreads();
  }
  int offp = partials[b] + s[t] - local;
  if (base < N)     { rowptr[base] = offp;          cursor[base] = offp; }
  if (base + 1 < N) { rowptr[base + 1] = offp + d0; cursor[base + 1] = offp + d0; }
  if (b == 0 && t == 0) rowptr[N] = E;
}

__global__ void csr_scatter(const int* __restrict__ ei, int* __restrict__ cursor,
                            int* __restrict__ adj, int E) {
  int e = blockIdx.x * 256 + threadIdx.x;
  if (e < E) {
    int dst = ei[E + e];
    int pos = atomicAdd(&cursor[dst], 1);
    adj[pos] = ei[e];
  }
}

// ---------------- fused projection GEMM: Y = X @ W + b  ----------------------
struct GemmOut { void* Y[4]; const float* bias[4]; };

#define LDP 136   // padded LDS row stride (bf16 elems)

__global__ __launch_bounds__(256) void gemm_proj(
    const unsigned short* __restrict__ X,
    const unsigned short* __restrict__ WB4,   // fragment-ordered, 4 mats x 16384
    GemmOut go, int N)
{
  __shared__ __align__(16) unsigned short xs[64 * LDP];

  const int proj = blockIdx.y;
  const unsigned short* __restrict__ WB = WB4 + proj * 16384;
  const float* __restrict__ bias = go.bias[proj];

  const int t = threadIdx.x;
  const int rowBase = blockIdx.x * 64;

#pragma unroll
  for (int j = 0; j < 4; ++j) {
    int v = t + 256 * j;
    int r = v >> 4;
    int ig = (v & 15) * 8;
    int grow = rowBase + r;
    uint4 val = make_uint4(0u, 0u, 0u, 0u);
    if (grow < N) val = *reinterpret_cast<const uint4*>(X + grow * 128 + ig);
    *reinterpret_cast<uint4*>(&xs[r * LDP + ig]) = val;
  }
  __syncthreads();

  const int wave = t >> 6;
  const int lane = t & 63;
  const int ln16 = lane & 15;
  const int quad = lane >> 4;
  const int r0 = wave * 16;

  f32x4 acc[8] = {};

#pragma unroll
  for (int kk = 0; kk < 4; ++kk) {
    bf16x8 a = *reinterpret_cast<const bf16x8*>(&xs[(r0 + ln16) * LDP + kk * 32 + quad * 8]);
#pragma unroll
    for (int ct = 0; ct < 8; ++ct) {
      bf16x8 b = *reinterpret_cast<const bf16x8*>(WB + ((kk * 8 + ct) * 64 + lane) * 8);
      acc[ct] = __builtin_amdgcn_mfma_f32_16x16x32_bf16(a, b, acc[ct], 0, 0, 0);
    }
  }

  const bool asHalf = (proj < 3);
  float* __restrict__ Yf = (float*)go.Y[proj];
  _Float16* __restrict__ Yh = (_Float16*)go.Y[proj];

#pragma unroll
  for (int ct = 0; ct < 8; ++ct) {
    int col = ct * 16 + ln16;
    float bv = bias[col];
#pragma unroll
    for (int reg = 0; reg < 4; ++reg) {
      int grow = rowBase + r0 + quad * 4 + reg;
      if (grow < N) {
        float v = acc[ct][reg] + bv;
        if (asHalf) Yh[grow * 128 + col] = (_Float16)v;
        else        Yf[grow * 128 + col] = v;
      }
    }
  }
}

// ---------------- fused per-node attention (gather, online softmax) ----------
__global__ __launch_bounds__(256) void node_attn(
    const int* __restrict__ rowptr, const int* __restrict__ adj,
    const _Float16* __restrict__ Q, const _Float16* __restrict__ K,
    const _Float16* __restrict__ V, float* __restrict__ H, int N)
{
  int n = blockIdx.x * 8 + (threadIdx.x >> 5);
  int lane = threadIdx.x & 31;
  if (n >= N) return;
  int p0 = rowptr[n], p1 = rowptr[n + 1];

  f16x4 qh = *reinterpret_cast<const f16x4*>(Q + n * 128 + lane * 4);
  float4 q = make_float4((float)qh.x, (float)qh.y, (float)qh.z, (float)qh.w);
  float m = -INFINITY, s = 0.f;
  float4 acc = make_float4(0.f, 0.f, 0.f, 0.f);

  int p = p0;
  for (; p + 1 < p1; p += 2) {
    int s0 = adj[p], s1 = adj[p + 1];
    f16x4 k0 = *reinterpret_cast<const f16x4*>(K + s0 * 128 + lane * 4);
    f16x4 k1 = *reinterpret_cast<const f16x4*>(K + s1 * 128 + lane * 4);
    float d0 = q.x * (float)k0.x + q.y * (float)k0.y + q.z * (float)k0.z + q.w * (float)k0.w;
    float d1 = q.x * (float)k1.x + q.y * (float)k1.y + q.z * (float)k1.z + q.w * (float)k1.w;
#pragma unroll
    for (int off = 16; off; off >>= 1) {
      d0 += __shfl_xor(d0, off, 32);
      d1 += __shfl_xor(d1, off, 32);
    }
    float l0 = d0 * 0.08838834764831845f;
    float l1 = d1 * 0.08838834764831845f;
    float mn = fmaxf(m, fmaxf(l0, l1));
    float sc = __expf(m - mn);
    float w0 = __expf(l0 - mn);
    float w1 = __expf(l1 - mn);
    f16x4 v0 = *reinterpret_cast<const f16x4*>(V + s0 * 128 + lane * 4);
    f16x4 v1 = *reinterpret_cast<const f16x4*>(V + s1 * 128 + lane * 4);
    acc.x = acc.x * sc + w0 * (float)v0.x + w1 * (float)v1.x;
    acc.y = acc.y * sc + w0 * (float)v0.y + w1 * (float)v1.y;
    acc.z = acc.z * sc + w0 * (float)v0.z + w1 * (float)v1.z;
    acc.w = acc.w * sc + w0 * (float)v0.w + w1 * (float)v1.w;
    s = s * sc + w0 + w1;
    m = mn;
  }
  if (p < p1) {
    int s0 = adj[p];
    f16x4 k0 = *reinterpret_cast<const f16x4*>(K + s0 * 128 + lane * 4);
    float d0 = q.x * (float)k0.x + q.y * (float)k0.y + q.z * (float)k0.z + q.w * (float)k0.w;
#pragma unroll
    for (int off = 16; off; off >>= 1) d0 += __shfl_xor(d0, off, 32);
    float l0 = d0 * 0.08838834764831845f;
    float mn = fmaxf(m, l0);
    float sc = __expf(m - mn);
    float w0 = __expf(l0 - mn);
    f16x4 v0 = *reinterpret_cast<const f16x4*>(V + s0 * 128 + lane * 4);
    acc.x = acc.x * sc + w0 * (float)v0.x;
    acc.y = acc.y * sc + w0 * (float)v0.y;
    acc.z = acc.z * sc + w0 * (float)v0.z;
    acc.w = acc.w * sc + w0 * (float)v0.w;
    s = s * sc + w0;
    m = mn;
  }

  float inv = 1.0f / (s + 1e-16f);
  float4 h = *reinterpret_cast<const float4*>(H + n * 128 + lane * 4);
  h.x += acc.x * inv;
  h.y += acc.y * inv;
  h.z += acc.z * inv;
  h.w += acc.w * inv;
  *reinterpret_cast<float4*>(H + n * 128 + lane * 4) = h;
}

// ---------------- batchnorm stats (high-occupancy, float4, LDS tree) ---------
// thread t: feature group fg = t&31 (4 feats), walker w = t>>5 (8 per block)
__global__ __launch_bounds__(256) void bn_stats(
    const float* __restrict__ H, float* __restrict__ bnsum,
    float* __restrict__ bnsq, int N)
{
  __shared__ float4 rs[256], rq[256];
  int t = threadIdx.x;
  int fg = t & 31, w = t >> 5;
  float4 s = make_float4(0.f, 0.f, 0.f, 0.f);
  float4 s2 = make_float4(0.f, 0.f, 0.f, 0.f);
  for (int row = blockIdx.x * 8 + w; row < N; row += BN_BLOCKS * 8) {
    float4 v = *reinterpret_cast<const float4*>(H + (size_t)row * 128 + fg * 4);
    s.x += v.x; s.y += v.y; s.z += v.z; s.w += v.w;
    s2.x += v.x * v.x; s2.y += v.y * v.y; s2.z += v.z * v.z; s2.w += v.w * v.w;
  }
  rs[t] = s; rq[t] = s2;
  __syncthreads();
#pragma unroll
  for (int off = 128; off >= 32; off >>= 1) {
    if (t < off) {
      float4 a = rs[t + off], b = rq[t + off];
      rs[t].x += a.x; rs[t].y += a.y; rs[t].z += a.z; rs[t].w += a.w;
      rq[t].x += b.x; rq[t].y += b.y; rq[t].z += b.z; rq[t].w += b.w;
    }
    __syncthreads();
  }
  if (t < 32) {
    float4 a = rs[t], b = rq[t];
    unsafeAtomicAdd(bnsum + t * 4 + 0, a.x);
    unsafeAtomicAdd(bnsum + t * 4 + 1, a.y);
    unsafeAtomicAdd(bnsum + t * 4 + 2, a.z);
    unsafeAtomicAdd(bnsum + t * 4 + 3, a.w);
    unsafeAtomicAdd(bnsq + t * 4 + 0, b.x);
    unsafeAtomicAdd(bnsq + t * 4 + 1, b.y);
    unsafeAtomicAdd(bnsq + t * 4 + 2, b.z);
    unsafeAtomicAdd(bnsq + t * 4 + 3, b.w);
  }
}

__global__ void bn_finalize(const float* __restrict__ bnsum, const float* __restrict__ bnsq,
                            const float* __restrict__ gamma,
                            const float* __restrict__ beta,
                            float* __restrict__ scale, float* __restrict__ shift, int N)
{
  int f = threadIdx.x;   // 128 threads
  float mean = bnsum[f] / (float)N;
  float var = bnsq[f] / (float)N - mean * mean;
  var = fmaxf(var, 0.f);
  float sc = gamma[f] * rsqrtf(var + 1e-5f);
  scale[f] = sc;
  shift[f] = beta[f] - mean * sc;
}

// ---------------- apply BN + relu, write bf16 for next layer -----------------
__global__ void bn_apply_relu(const float* __restrict__ H, const float* __restrict__ scale,
                              const float* __restrict__ shift, unsigned short* __restrict__ Xb,
                              int total)
{
  int i4 = (blockIdx.x * 256 + threadIdx.x) * 4;
  if (i4 >= total) return;
  int f = i4 & 127;
  float4 h = *reinterpret_cast<const float4*>(H + i4);
  float4 sc = *reinterpret_cast<const float4*>(scale + f);
  float4 sh = *reinterpret_cast<const float4*>(shift + f);
  ushort4 o;
  o.x = f2bf(fmaxf(h.x * sc.x + sh.x, 0.f));
  o.y = f2bf(fmaxf(h.y * sc.y + sh.y, 0.f));
  o.z = f2bf(fmaxf(h.z * sc.z + sh.z, 0.f));
  o.w = f2bf(fmaxf(h.w * sc.w + sh.w, 0.f));
  *reinterpret_cast<ushort4*>(Xb + i4) = o;
}

// ---------------- per-graph pool (BN+ReLU fused) + linear head ---------------
__global__ __launch_bounds__(256) void pool_linear(
    const float* __restrict__ H, const float* __restrict__ scale,
    const float* __restrict__ shift, const int* __restrict__ batch,
    const float* __restrict__ Wlin, const float* __restrict__ blin,
    float* __restrict__ out, int N)
{
  __shared__ float red[256];
  __shared__ float pool[128];
  int g = blockIdx.x;
  int t = threadIdx.x;

  int lo = 0, hi = N;
  while (lo < hi) { int mid = (lo + hi) >> 1; if (batch[mid] < g) lo = mid + 1; else hi = mid; }
  int start = lo;
  hi = N;
  while (lo < hi) { int mid = (lo + hi) >> 1; if (batch[mid] < g + 1) lo = mid + 1; else hi = mid; }
  int end = lo;
  int cnt = end - start;

  int f = t & 127, half = t >> 7;
  float sc = scale[f], sh = shift[f];
  float s = 0.f;
  for (int row = start + half; row < end; row += 2)
    s += fmaxf(H[row * 128 + f] * sc + sh, 0.f);
  red[t] = s;
  __syncthreads();
  if (t < 128)
    pool[t] = (red[t] + red[t + 128]) / fmaxf((float)cnt, 1.f);
  __syncthreads();

  if (t < 20) {
    float acc = 0.f;
#pragma unroll 4
    for (int i = 0; i < 128; ++i)
      acc += pool[i] * Wlin[i * 20 + t];
    out[g * 20 + t] = acc + blin[t];
  }
}

// =============================================================================
extern "C" void kernel_launch(void* const* d_in, const int* in_sizes, int n_in,
                              void* d_out, int out_size, void* d_ws, size_t ws_size,
                              hipStream_t stream)
{
  const int N = N_NODES, E = N_EDGES, G = N_GRAPHS;

  const float* x = (const float*)d_in[0];
  const int* ei = (const int*)d_in[1];
  const int* batch = (const int*)d_in[2];
  const float* Wlin = (const float*)d_in[33];
  const float* blin = (const float*)d_in[34];

  char* ws = (char*)d_ws;
  size_t off = 0;
  auto alloc = [&](size_t bytes) -> void* {
    void* p = ws + off;
    off = (off + bytes + 255) & ~(size_t)255;
    return p;
  };
  unsigned short* WB = (unsigned short*)alloc(12 * 16384 * sizeof(unsigned short));
  _Float16* Qh  = (_Float16*)alloc((size_t)N * 128 * 2);
  _Float16* Kh  = (_Float16*)alloc((size_t)N * 128 * 2);
  _Float16* Vh  = (_Float16*)alloc((size_t)N * 128 * 2);
  float* H      = (float*)alloc((size_t)N * 128 * 4);
  int* deg      = (int*)alloc((size_t)N * 4);
  int* rowptr   = (int*)alloc((size_t)(N + 1) * 4);
  int* cursor   = (int*)alloc((size_t)N * 4);
  int* adj      = (int*)alloc((size_t)E * 4);
  int* partials = (int*)alloc((size_t)N_CHUNKS * 4);
  float* bnsum  = (float*)alloc(128 * 4);       // bnsq contiguous after
  float* bnsq   = (float*)alloc(128 * 4);
  float* scale  = (float*)alloc(128 * 4);
  float* shift  = (float*)alloc(128 * 4);
  unsigned short* Xb = (unsigned short*)alloc((size_t)N * 128 * 2);

  // ---- one-time per launch: weight repack, x->bf16, CSR build ----
  WPtrs wp;
  for (int L = 0; L < 3; ++L) {
    wp.w[L * 4 + 0] = (const float*)d_in[3 + L * 10 + 0];  // Wq
    wp.w[L * 4 + 1] = (const float*)d_in[3 + L * 10 + 2];  // Wk
    wp.w[L * 4 + 2] = (const float*)d_in[3 + L * 10 + 4];  // Wv
    wp.w[L * 4 + 3] = (const float*)d_in[3 + L * 10 + 6];  // Ws
  }
  repack_kernel<<<dim3(64, 12), 256, 0, stream>>>(wp, WB);
  f32_to_bf16<<<(N * 128 / 4 + 255) / 256, 256, 0, stream>>>(x, Xb, N * 128 / 4);

  hipMemsetAsync(deg, 0, (size_t)N * 4, stream);
  deg_count<<<(E + 255) / 256, 256, 0, stream>>>(ei, deg, E);
  scan_sum<<<N_CHUNKS, 256, 0, stream>>>(deg, partials, N);
  scan_partials<<<1, 128, 0, stream>>>(partials);
  scan_apply<<<N_CHUNKS, 256, 0, stream>>>(deg, partials, rowptr, cursor, N, E);
  csr_scatter<<<(E + 255) / 256, 256, 0, stream>>>(ei, cursor, adj, E);

  for (int L = 0; L < 3; ++L) {
    GemmOut go;
    go.Y[0] = Qh; go.Y[1] = Kh; go.Y[2] = Vh; go.Y[3] = H;
    go.bias[0] = (const float*)d_in[3 + L * 10 + 1];
    go.bias[1] = (const float*)d_in[3 + L * 10 + 3];
    go.bias[2] = (const float*)d_in[3 + L * 10 + 5];
    go.bias[3] = (const float*)d_in[3 + L * 10 + 7];
    gemm_proj<<<dim3((N + 63) / 64, 4), 256, 0, stream>>>(Xb, WB + L * 4 * 16384, go, N);

    node_attn<<<(N + 7) / 8, 256, 0, stream>>>(rowptr, adj, Qh, Kh, Vh, H, N);

    hipMemsetAsync(bnsum, 0, 2 * 128 * 4, stream);       // bnsum + bnsq
    bn_stats<<<BN_BLOCKS, 256, 0, stream>>>(H, bnsum, bnsq, N);
    bn_finalize<<<1, 128, 0, stream>>>(bnsum, bnsq,
        (const float*)d_in[3 + L * 10 + 8],
        (const float*)d_in[3 + L * 10 + 9],
        scale, shift, N);

    if (L < 2) {
      bn_apply_relu<<<(N * 128 / 4 + 255) / 256, 256, 0, stream>>>(H, scale, shift, Xb, N * 128);
    } else {
      pool_linear<<<G, 256, 0, stream>>>(H, scale, shift, batch, Wlin, blin,
                                         (float*)d_out, N);
    }
  }
}

// Round 9
// 521.775 us; speedup vs baseline: 1.2499x; 1.2499x over previous
//
#include <hip/hip_runtime.h>

#define N_NODES 50000
#define N_EDGES 400000
#define DH 128
#define N_GRAPHS 256

#define SCAN_CHUNK 512
#define N_CHUNKS ((N_NODES + SCAN_CHUNK - 1) / SCAN_CHUNK)   // 98
#define ATTN_BLOCKS ((N_NODES + 7) / 8)                      // 6250

typedef __bf16 bf16x8 __attribute__((ext_vector_type(8)));
typedef float f32x4 __attribute__((ext_vector_type(4)));
typedef _Float16 f16x4 __attribute__((ext_vector_type(4)));

#define DEV __device__ __forceinline__

DEV unsigned short f2bf(float f) {
  union { float f; unsigned int i; } v; v.f = f;
  unsigned int x = v.i;
  unsigned int r = (x + 0x7fffu + ((x >> 16) & 1u)) >> 16;
  return (unsigned short)r;
}

// ---- weight repack into MFMA B-fragment order ------------------------------
struct WPtrs { const float* w[12]; };

__global__ void repack_kernel(WPtrs wp, unsigned short* __restrict__ WB) {
  int mat = blockIdx.y;
  int m = blockIdx.x * 256 + threadIdx.x;   // 0..16383
  int j = m & 7;
  int lane = (m >> 3) & 63;
  int ct = (m >> 9) & 7;
  int kk = m >> 12;
  int i = kk * 32 + (lane >> 4) * 8 + j;
  int o = ct * 16 + (lane & 15);
  WB[mat * 16384 + m] = f2bf(wp.w[mat][i * 128 + o]);
}

// ---------------- fp32 -> bf16 convert (layer-0 x) ---------------------------
__global__ void f32_to_bf16(const float* __restrict__ in, unsigned short* __restrict__ out,
                            int total4) {
  int i = blockIdx.x * 256 + threadIdx.x;
  if (i >= total4) return;
  float4 v = *reinterpret_cast<const float4*>(in + i * 4);
  ushort4 o;
  o.x = f2bf(v.x); o.y = f2bf(v.y); o.z = f2bf(v.z); o.w = f2bf(v.w);
  *reinterpret_cast<ushort4*>(out + i * 4) = o;
}

// ---------------- CSR build --------------------------------------------------
__global__ void deg_count(const int* __restrict__ ei, int* __restrict__ deg, int E) {
  int e = blockIdx.x * 256 + threadIdx.x;
  if (e < E) atomicAdd(&deg[ei[E + e]], 1);
}

__global__ __launch_bounds__(256) void scan_sum(const int* __restrict__ deg,
                                                int* __restrict__ partials, int N) {
  __shared__ int red[256];
  int b = blockIdx.x, t = threadIdx.x;
  int base = b * SCAN_CHUNK + t * 2;
  int s = 0;
  if (base + 1 < N) { int2 v = *reinterpret_cast<const int2*>(deg + base); s = v.x + v.y; }
  else if (base < N) s = deg[base];
  red[t] = s;
  __syncthreads();
  for (int off = 128; off; off >>= 1) {
    if (t < off) red[t] += red[t + off];
    __syncthreads();
  }
  if (t == 0) partials[b] = red[0];
}

__global__ __launch_bounds__(128) void scan_partials(int* __restrict__ partials) {
  __shared__ int s[128];
  int t = threadIdx.x;
  int v = (t < N_CHUNKS) ? partials[t] : 0;
  s[t] = v;
  __syncthreads();
  for (int off = 1; off < 128; off <<= 1) {
    int o = (t >= off) ? s[t - off] : 0;
    __syncthreads();
    s[t] += o;
    __syncthreads();
  }
  if (t < N_CHUNKS) partials[t] = s[t] - v;   // exclusive
}

__global__ __launch_bounds__(256) void scan_apply(const int* __restrict__ deg,
                                                  const int* __restrict__ partials,
                                                  int* __restrict__ rowptr,
                                                  int* __restrict__ cursor, int N, int E) {
  __shared__ int s[256];
  int b = blockIdx.x, t = threadIdx.x;
  int base = b * SCAN_CHUNK + t * 2;
  int d0 = 0, d1 = 0;
  if (base + 1 < N) { int2 v = *reinterpret_cast<const int2*>(deg + base); d0 = v.x; d1 = v.y; }
  else if (base < N) d0 = deg[base];
  int local = d0 + d1;
  s[t] = local;
  __syncthreads();
  for (int off = 1; off < 256; off <<= 1) {
    int o = (t >= off) ? s[t - off] : 0;
    __syncthreads();
    s[t] += o;
    __syncthreads();
  }
  int offp = partials[b] + s[t] - local;
  if (base < N)     { rowptr[base] = offp;          cursor[base] = offp; }
  if (base + 1 < N) { rowptr[base + 1] = offp + d0; cursor[base + 1] = offp + d0; }
  if (b == 0 && t == 0) rowptr[N] = E;
}

__global__ void csr_scatter(const int* __restrict__ ei, int* __restrict__ cursor,
                            int* __restrict__ adj, int E) {
  int e = blockIdx.x * 256 + threadIdx.x;
  if (e < E) {
    int dst = ei[E + e];
    int pos = atomicAdd(&cursor[dst], 1);
    adj[pos] = ei[e];
  }
}

// ---------------- fused projection GEMM: Y = (BN(X)) @ W + b -----------------
// useBN=0: stage bf16 Xb. useBN=1: stage fp32 Hin with scale/shift+ReLU fused.
struct GemmOut { void* Y[4]; const float* bias[4]; };

#define LDP 136   // padded LDS row stride (bf16 elems)

__global__ __launch_bounds__(256) void gemm_proj(
    const unsigned short* __restrict__ X,
    const float* __restrict__ Hin,
    const float* __restrict__ scale, const float* __restrict__ shift,
    const unsigned short* __restrict__ WB4,   // fragment-ordered, 4 mats x 16384
    GemmOut go, int useBN, int N)
{
  __shared__ __align__(16) unsigned short xs[64 * LDP];

  const int proj = blockIdx.y;
  const unsigned short* __restrict__ WB = WB4 + proj * 16384;
  const float* __restrict__ bias = go.bias[proj];

  const int t = threadIdx.x;
  const int rowBase = blockIdx.x * 64;
  const int igc = (t & 15) * 8;

  if (useBN) {
    float4 sc0 = *reinterpret_cast<const float4*>(scale + igc);
    float4 sc1 = *reinterpret_cast<const float4*>(scale + igc + 4);
    float4 sh0 = *reinterpret_cast<const float4*>(shift + igc);
    float4 sh1 = *reinterpret_cast<const float4*>(shift + igc + 4);
#pragma unroll
    for (int j = 0; j < 4; ++j) {
      int v = t + 256 * j;
      int r = v >> 4;
      int grow = rowBase + r;
      ushort4 o0 = make_ushort4(0, 0, 0, 0), o1 = make_ushort4(0, 0, 0, 0);
      if (grow < N) {
        float4 a = *reinterpret_cast<const float4*>(Hin + (size_t)grow * 128 + igc);
        float4 b = *reinterpret_cast<const float4*>(Hin + (size_t)grow * 128 + igc + 4);
        o0.x = f2bf(fmaxf(a.x * sc0.x + sh0.x, 0.f));
        o0.y = f2bf(fmaxf(a.y * sc0.y + sh0.y, 0.f));
        o0.z = f2bf(fmaxf(a.z * sc0.z + sh0.z, 0.f));
        o0.w = f2bf(fmaxf(a.w * sc0.w + sh0.w, 0.f));
        o1.x = f2bf(fmaxf(b.x * sc1.x + sh1.x, 0.f));
        o1.y = f2bf(fmaxf(b.y * sc1.y + sh1.y, 0.f));
        o1.z = f2bf(fmaxf(b.z * sc1.z + sh1.z, 0.f));
        o1.w = f2bf(fmaxf(b.w * sc1.w + sh1.w, 0.f));
      }
      *reinterpret_cast<ushort4*>(&xs[r * LDP + igc]) = o0;
      *reinterpret_cast<ushort4*>(&xs[r * LDP + igc + 4]) = o1;
    }
  } else {
#pragma unroll
    for (int j = 0; j < 4; ++j) {
      int v = t + 256 * j;
      int r = v >> 4;
      int grow = rowBase + r;
      uint4 val = make_uint4(0u, 0u, 0u, 0u);
      if (grow < N) val = *reinterpret_cast<const uint4*>(X + (size_t)grow * 128 + igc);
      *reinterpret_cast<uint4*>(&xs[r * LDP + igc]) = val;
    }
  }
  __syncthreads();

  const int wave = t >> 6;
  const int lane = t & 63;
  const int ln16 = lane & 15;
  const int quad = lane >> 4;
  const int r0 = wave * 16;

  f32x4 acc[8] = {};

#pragma unroll
  for (int kk = 0; kk < 4; ++kk) {
    bf16x8 a = *reinterpret_cast<const bf16x8*>(&xs[(r0 + ln16) * LDP + kk * 32 + quad * 8]);
#pragma unroll
    for (int ct = 0; ct < 8; ++ct) {
      bf16x8 b = *reinterpret_cast<const bf16x8*>(WB + ((kk * 8 + ct) * 64 + lane) * 8);
      acc[ct] = __builtin_amdgcn_mfma_f32_16x16x32_bf16(a, b, acc[ct], 0, 0, 0);
    }
  }

  const bool asHalf = (proj < 3);
  float* __restrict__ Yf = (float*)go.Y[proj];
  _Float16* __restrict__ Yh = (_Float16*)go.Y[proj];

#pragma unroll
  for (int ct = 0; ct < 8; ++ct) {
    int col = ct * 16 + ln16;
    float bv = bias[col];
#pragma unroll
    for (int reg = 0; reg < 4; ++reg) {
      int grow = rowBase + r0 + quad * 4 + reg;
      if (grow < N) {
        float v = acc[ct][reg] + bv;
        if (asHalf) Yh[grow * 128 + col] = (_Float16)v;
        else        Yf[grow * 128 + col] = v;
      }
    }
  }
}

// ---------------- fused per-node attention + BN partial stats ----------------
// 32 lanes per dst node, 8 nodes/block. Epilogue: block-level sum/sum^2 over
// the 8 nodes -> Pbuf[block][256] (128 sums | 128 sumsqs), no atomics.
__global__ __launch_bounds__(256) void node_attn(
    const int* __restrict__ rowptr, const int* __restrict__ adj,
    const _Float16* __restrict__ Q, const _Float16* __restrict__ K,
    const _Float16* __restrict__ V, float* __restrict__ H,
    float* __restrict__ Pbuf, int N)
{
  __shared__ float lsum[8][128];
  __shared__ float lsq[8][128];
  int t = threadIdx.x;
  int w = t >> 5, lane = t & 31;
  int n = blockIdx.x * 8 + w;
  bool valid = n < N;
  int nn = valid ? n : 0;
  int p0 = 0, p1 = 0;
  if (valid) { p0 = rowptr[n]; p1 = rowptr[n + 1]; }

  f16x4 qh = *reinterpret_cast<const f16x4*>(Q + (size_t)nn * 128 + lane * 4);
  float4 q = make_float4((float)qh.x, (float)qh.y, (float)qh.z, (float)qh.w);
  float m = -INFINITY, s = 0.f;
  float4 acc = make_float4(0.f, 0.f, 0.f, 0.f);

  int p = p0;
  for (; p + 1 < p1; p += 2) {
    int s0 = adj[p], s1 = adj[p + 1];
    f16x4 k0 = *reinterpret_cast<const f16x4*>(K + (size_t)s0 * 128 + lane * 4);
    f16x4 k1 = *reinterpret_cast<const f16x4*>(K + (size_t)s1 * 128 + lane * 4);
    float d0 = q.x * (float)k0.x + q.y * (float)k0.y + q.z * (float)k0.z + q.w * (float)k0.w;
    float d1 = q.x * (float)k1.x + q.y * (float)k1.y + q.z * (float)k1.z + q.w * (float)k1.w;
#pragma unroll
    for (int off = 16; off; off >>= 1) {
      d0 += __shfl_xor(d0, off, 32);
      d1 += __shfl_xor(d1, off, 32);
    }
    float l0 = d0 * 0.08838834764831845f;
    float l1 = d1 * 0.08838834764831845f;
    float mn = fmaxf(m, fmaxf(l0, l1));
    float sc = __expf(m - mn);
    float w0 = __expf(l0 - mn);
    float w1 = __expf(l1 - mn);
    f16x4 v0 = *reinterpret_cast<const f16x4*>(V + (size_t)s0 * 128 + lane * 4);
    f16x4 v1 = *reinterpret_cast<const f16x4*>(V + (size_t)s1 * 128 + lane * 4);
    acc.x = acc.x * sc + w0 * (float)v0.x + w1 * (float)v1.x;
    acc.y = acc.y * sc + w0 * (float)v0.y + w1 * (float)v1.y;
    acc.z = acc.z * sc + w0 * (float)v0.z + w1 * (float)v1.z;
    acc.w = acc.w * sc + w0 * (float)v0.w + w1 * (float)v1.w;
    s = s * sc + w0 + w1;
    m = mn;
  }
  if (p < p1) {
    int s0 = adj[p];
    f16x4 k0 = *reinterpret_cast<const f16x4*>(K + (size_t)s0 * 128 + lane * 4);
    float d0 = q.x * (float)k0.x + q.y * (float)k0.y + q.z * (float)k0.z + q.w * (float)k0.w;
#pragma unroll
    for (int off = 16; off; off >>= 1) d0 += __shfl_xor(d0, off, 32);
    float l0 = d0 * 0.08838834764831845f;
    float mn = fmaxf(m, l0);
    float sc = __expf(m - mn);
    float w0 = __expf(l0 - mn);
    f16x4 v0 = *reinterpret_cast<const f16x4*>(V + (size_t)s0 * 128 + lane * 4);
    acc.x = acc.x * sc + w0 * (float)v0.x;
    acc.y = acc.y * sc + w0 * (float)v0.y;
    acc.z = acc.z * sc + w0 * (float)v0.z;
    acc.w = acc.w * sc + w0 * (float)v0.w;
    s = s * sc + w0;
    m = mn;
  }

  float4 h = make_float4(0.f, 0.f, 0.f, 0.f);
  if (valid) {
    float inv = 1.0f / (s + 1e-16f);
    h = *reinterpret_cast<const float4*>(H + (size_t)n * 128 + lane * 4);
    h.x += acc.x * inv;
    h.y += acc.y * inv;
    h.z += acc.z * inv;
    h.w += acc.w * inv;
    *reinterpret_cast<float4*>(H + (size_t)n * 128 + lane * 4) = h;
  }

  // BN partial stats over this block's 8 nodes
  *reinterpret_cast<float4*>(&lsum[w][lane * 4]) = h;
  float4 h2 = make_float4(h.x * h.x, h.y * h.y, h.z * h.z, h.w * h.w);
  *reinterpret_cast<float4*>(&lsq[w][lane * 4]) = h2;
  __syncthreads();

  int f = t & 127;
  float a = 0.f;
  if (t < 128) {
#pragma unroll
    for (int n8 = 0; n8 < 8; ++n8) a += lsum[n8][f];
  } else {
#pragma unroll
    for (int n8 = 0; n8 < 8; ++n8) a += lsq[n8][f];
  }
  Pbuf[(size_t)blockIdx.x * 256 + t] = a;
}

// ---------------- BN reduce: 6250x256 partials -> 64x256 -> scale/shift ------
__global__ __launch_bounds__(256) void bn_reduceA(const float* __restrict__ Pbuf,
                                                  float* __restrict__ partial) {
  int t = threadIdx.x;
  float s0 = 0.f, s1 = 0.f, s2 = 0.f, s3 = 0.f;
  int r = blockIdx.x;
  for (; r + 192 < ATTN_BLOCKS; r += 256) {
    s0 += Pbuf[(size_t)(r      ) * 256 + t];
    s1 += Pbuf[(size_t)(r +  64) * 256 + t];
    s2 += Pbuf[(size_t)(r + 128) * 256 + t];
    s3 += Pbuf[(size_t)(r + 192) * 256 + t];
  }
  for (; r < ATTN_BLOCKS; r += 64) s0 += Pbuf[(size_t)r * 256 + t];
  partial[blockIdx.x * 256 + t] = s0 + s1 + s2 + s3;
}

__global__ __launch_bounds__(256) void bn_reduceB(
    const float* __restrict__ partial,
    const float* __restrict__ gamma, const float* __restrict__ beta,
    float* __restrict__ scale, float* __restrict__ shift, int N)
{
  __shared__ float red[256];
  int t = threadIdx.x;
  float s0 = 0.f, s1 = 0.f, s2 = 0.f, s3 = 0.f;
#pragma unroll
  for (int r = 0; r < 64; r += 4) {
    s0 += partial[(r + 0) * 256 + t];
    s1 += partial[(r + 1) * 256 + t];
    s2 += partial[(r + 2) * 256 + t];
    s3 += partial[(r + 3) * 256 + t];
  }
  red[t] = s0 + s1 + s2 + s3;
  __syncthreads();
  if (t < 128) {
    float mean = red[t] / (float)N;
    float var = red[t + 128] / (float)N - mean * mean;
    var = fmaxf(var, 0.f);
    float sc = gamma[t] * rsqrtf(var + 1e-5f);
    scale[t] = sc;
    shift[t] = beta[t] - mean * sc;
  }
}

// ---------------- per-graph pool (BN+ReLU fused) + linear head ---------------
__global__ __launch_bounds__(256) void pool_linear(
    const float* __restrict__ H, const float* __restrict__ scale,
    const float* __restrict__ shift, const int* __restrict__ batch,
    const float* __restrict__ Wlin, const float* __restrict__ blin,
    float* __restrict__ out, int N)
{
  __shared__ float red[256];
  __shared__ float pool[128];
  int g = blockIdx.x;
  int t = threadIdx.x;

  int lo = 0, hi = N;
  while (lo < hi) { int mid = (lo + hi) >> 1; if (batch[mid] < g) lo = mid + 1; else hi = mid; }
  int start = lo;
  hi = N;
  while (lo < hi) { int mid = (lo + hi) >> 1; if (batch[mid] < g + 1) lo = mid + 1; else hi = mid; }
  int end = lo;
  int cnt = end - start;

  int f = t & 127, half = t >> 7;
  float sc = scale[f], sh = shift[f];
  float s = 0.f;
  for (int row = start + half; row < end; row += 2)
    s += fmaxf(H[(size_t)row * 128 + f] * sc + sh, 0.f);
  red[t] = s;
  __syncthreads();
  if (t < 128)
    pool[t] = (red[t] + red[t + 128]) / fmaxf((float)cnt, 1.f);
  __syncthreads();

  if (t < 20) {
    float acc = 0.f;
#pragma unroll 4
    for (int i = 0; i < 128; ++i)
      acc += pool[i] * Wlin[i * 20 + t];
    out[g * 20 + t] = acc + blin[t];
  }
}

// =============================================================================
extern "C" void kernel_launch(void* const* d_in, const int* in_sizes, int n_in,
                              void* d_out, int out_size, void* d_ws, size_t ws_size,
                              hipStream_t stream)
{
  const int N = N_NODES, E = N_EDGES, G = N_GRAPHS;

  const float* x = (const float*)d_in[0];
  const int* ei = (const int*)d_in[1];
  const int* batch = (const int*)d_in[2];
  const float* Wlin = (const float*)d_in[33];
  const float* blin = (const float*)d_in[34];

  char* ws = (char*)d_ws;
  size_t off = 0;
  auto alloc = [&](size_t bytes) -> void* {
    void* p = ws + off;
    off = (off + bytes + 255) & ~(size_t)255;
    return p;
  };
  unsigned short* WB = (unsigned short*)alloc(12 * 16384 * sizeof(unsigned short));
  _Float16* Qh  = (_Float16*)alloc((size_t)N * 128 * 2);
  _Float16* Kh  = (_Float16*)alloc((size_t)N * 128 * 2);
  _Float16* Vh  = (_Float16*)alloc((size_t)N * 128 * 2);
  float* H      = (float*)alloc((size_t)N * 128 * 4);
  int* deg      = (int*)alloc((size_t)N * 4);
  int* rowptr   = (int*)alloc((size_t)(N + 1) * 4);
  int* cursor   = (int*)alloc((size_t)N * 4);
  int* adj      = (int*)alloc((size_t)E * 4);
  int* partials = (int*)alloc((size_t)N_CHUNKS * 4);
  float* Pbuf   = (float*)alloc((size_t)ATTN_BLOCKS * 256 * 4);
  float* bnpart = (float*)alloc((size_t)64 * 256 * 4);
  float* scale  = (float*)alloc(128 * 4);
  float* shift  = (float*)alloc(128 * 4);
  unsigned short* Xb = (unsigned short*)alloc((size_t)N * 128 * 2);

  // ---- one-time per launch: weight repack, x->bf16, CSR build ----
  WPtrs wp;
  for (int L = 0; L < 3; ++L) {
    wp.w[L * 4 + 0] = (const float*)d_in[3 + L * 10 + 0];  // Wq
    wp.w[L * 4 + 1] = (const float*)d_in[3 + L * 10 + 2];  // Wk
    wp.w[L * 4 + 2] = (const float*)d_in[3 + L * 10 + 4];  // Wv
    wp.w[L * 4 + 3] = (const float*)d_in[3 + L * 10 + 6];  // Ws
  }
  repack_kernel<<<dim3(64, 12), 256, 0, stream>>>(wp, WB);
  f32_to_bf16<<<(N * 128 / 4 + 255) / 256, 256, 0, stream>>>(x, Xb, N * 128 / 4);

  hipMemsetAsync(deg, 0, (size_t)N * 4, stream);
  deg_count<<<(E + 255) / 256, 256, 0, stream>>>(ei, deg, E);
  scan_sum<<<N_CHUNKS, 256, 0, stream>>>(deg, partials, N);
  scan_partials<<<1, 128, 0, stream>>>(partials);
  scan_apply<<<N_CHUNKS, 256, 0, stream>>>(deg, partials, rowptr, cursor, N, E);
  csr_scatter<<<(E + 255) / 256, 256, 0, stream>>>(ei, cursor, adj, E);

  for (int L = 0; L < 3; ++L) {
    GemmOut go;
    go.Y[0] = Qh; go.Y[1] = Kh; go.Y[2] = Vh; go.Y[3] = H;
    go.bias[0] = (const float*)d_in[3 + L * 10 + 1];
    go.bias[1] = (const float*)d_in[3 + L * 10 + 3];
    go.bias[2] = (const float*)d_in[3 + L * 10 + 5];
    go.bias[3] = (const float*)d_in[3 + L * 10 + 7];
    // L0: bf16 Xb input.  L1/L2: fp32 H input with fused BN+ReLU (scale/shift
    // from previous layer's bn_reduceB).
    gemm_proj<<<dim3((N + 63) / 64, 4), 256, 0, stream>>>(
        Xb, H, scale, shift, WB + L * 4 * 16384, go, (L > 0) ? 1 : 0, N);

    node_attn<<<ATTN_BLOCKS, 256, 0, stream>>>(rowptr, adj, Qh, Kh, Vh, H, Pbuf, N);

    bn_reduceA<<<64, 256, 0, stream>>>(Pbuf, bnpart);
    bn_reduceB<<<1, 256, 0, stream>>>(bnpart,
        (const float*)d_in[3 + L * 10 + 8],
        (const float*)d_in[3 + L * 10 + 9],
        scale, shift, N);

    if (L == 2) {
      pool_linear<<<G, 256, 0, stream>>>(H, scale, shift, batch, Wlin, blin,
                                         (float*)d_out, N);
    }
  }
}

// Round 10
// 496.684 us; speedup vs baseline: 1.3130x; 1.0505x over previous
//
#include <hip/hip_runtime.h>

#define N_NODES 50000
#define N_EDGES 400000
#define DH 128
#define N_GRAPHS 256

#define SCAN_CHUNK 512
#define N_CHUNKS ((N_NODES + SCAN_CHUNK - 1) / SCAN_CHUNK)   // 98
#define ATTN_BLOCKS ((N_NODES + 7) / 8)                      // 6250

typedef __bf16 bf16x8 __attribute__((ext_vector_type(8)));
typedef float f32x4 __attribute__((ext_vector_type(4)));
typedef _Float16 f16x4 __attribute__((ext_vector_type(4)));

#define DEV __device__ __forceinline__

DEV unsigned short f2bf(float f) {
  union { float f; unsigned int i; } v; v.f = f;
  unsigned int x = v.i;
  unsigned int r = (x + 0x7fffu + ((x >> 16) & 1u)) >> 16;
  return (unsigned short)r;
}

// ---- weight repack into MFMA B-fragment order ------------------------------
struct WPtrs { const float* w[12]; };

__global__ void repack_kernel(WPtrs wp, unsigned short* __restrict__ WB) {
  int mat = blockIdx.y;
  int m = blockIdx.x * 256 + threadIdx.x;   // 0..16383
  int j = m & 7;
  int lane = (m >> 3) & 63;
  int ct = (m >> 9) & 7;
  int kk = m >> 12;
  int i = kk * 32 + (lane >> 4) * 8 + j;
  int o = ct * 16 + (lane & 15);
  WB[mat * 16384 + m] = f2bf(wp.w[mat][i * 128 + o]);
}

// ---------------- fp32 -> bf16 convert (layer-0 x) ---------------------------
__global__ void f32_to_bf16(const float* __restrict__ in, unsigned short* __restrict__ out,
                            int total4) {
  int i = blockIdx.x * 256 + threadIdx.x;
  if (i >= total4) return;
  float4 v = *reinterpret_cast<const float4*>(in + i * 4);
  ushort4 o;
  o.x = f2bf(v.x); o.y = f2bf(v.y); o.z = f2bf(v.z); o.w = f2bf(v.w);
  *reinterpret_cast<ushort4*>(out + i * 4) = o;
}

// ---------------- CSR build --------------------------------------------------
__global__ void deg_count(const int* __restrict__ ei, int* __restrict__ deg, int E) {
  int e = blockIdx.x * 256 + threadIdx.x;
  if (e < E) atomicAdd(&deg[ei[E + e]], 1);
}

__global__ __launch_bounds__(256) void scan_sum(const int* __restrict__ deg,
                                                int* __restrict__ partials, int N) {
  __shared__ int red[256];
  int b = blockIdx.x, t = threadIdx.x;
  int base = b * SCAN_CHUNK + t * 2;
  int s = 0;
  if (base + 1 < N) { int2 v = *reinterpret_cast<const int2*>(deg + base); s = v.x + v.y; }
  else if (base < N) s = deg[base];
  red[t] = s;
  __syncthreads();
  for (int off = 128; off; off >>= 1) {
    if (t < off) red[t] += red[t + off];
    __syncthreads();
  }
  if (t == 0) partials[b] = red[0];
}

__global__ __launch_bounds__(128) void scan_partials(int* __restrict__ partials) {
  __shared__ int s[128];
  int t = threadIdx.x;
  int v = (t < N_CHUNKS) ? partials[t] : 0;
  s[t] = v;
  __syncthreads();
  for (int off = 1; off < 128; off <<= 1) {
    int o = (t >= off) ? s[t - off] : 0;
    __syncthreads();
    s[t] += o;
    __syncthreads();
  }
  if (t < N_CHUNKS) partials[t] = s[t] - v;   // exclusive
}

__global__ __launch_bounds__(256) void scan_apply(const int* __restrict__ deg,
                                                  const int* __restrict__ partials,
                                                  int* __restrict__ rowptr,
                                                  int* __restrict__ cursor, int N, int E) {
  __shared__ int s[256];
  int b = blockIdx.x, t = threadIdx.x;
  int base = b * SCAN_CHUNK + t * 2;
  int d0 = 0, d1 = 0;
  if (base + 1 < N) { int2 v = *reinterpret_cast<const int2*>(deg + base); d0 = v.x; d1 = v.y; }
  else if (base < N) d0 = deg[base];
  int local = d0 + d1;
  s[t] = local;
  __syncthreads();
  for (int off = 1; off < 256; off <<= 1) {
    int o = (t >= off) ? s[t - off] : 0;
    __syncthreads();
    s[t] += o;
    __syncthreads();
  }
  int offp = partials[b] + s[t] - local;
  if (base < N)     { rowptr[base] = offp;          cursor[base] = offp; }
  if (base + 1 < N) { rowptr[base + 1] = offp + d0; cursor[base + 1] = offp + d0; }
  if (b == 0 && t == 0) rowptr[N] = E;
}

__global__ void csr_scatter(const int* __restrict__ ei, int* __restrict__ cursor,
                            int* __restrict__ adj, int E) {
  int e = blockIdx.x * 256 + threadIdx.x;
  if (e < E) {
    int dst = ei[E + e];
    int pos = atomicAdd(&cursor[dst], 1);
    adj[pos] = ei[e];
  }
}

// ---------------- fused 4-projection GEMM: {Q,K,V,H} = BN(X) @ W_p + b_p -----
// One block stages its 64-row X tile ONCE, then loops over the 4 projections
// (B-fragments L2-resident, accumulators reused serially -> low VGPR).
struct GemmOut { void* Y[4]; const float* bias[4]; };

#define LDP 136   // padded LDS row stride (bf16 elems)

__global__ __launch_bounds__(256) void gemm_proj(
    const unsigned short* __restrict__ X,
    const float* __restrict__ Hin,
    const float* __restrict__ scale, const float* __restrict__ shift,
    const unsigned short* __restrict__ WB4,   // fragment-ordered, 4 mats x 16384
    GemmOut go, int useBN, int N)
{
  __shared__ __align__(16) unsigned short xs[64 * LDP];

  const int t = threadIdx.x;
  const int rowBase = blockIdx.x * 64;
  const int igc = (t & 15) * 8;

  if (useBN) {
    float4 sc0 = *reinterpret_cast<const float4*>(scale + igc);
    float4 sc1 = *reinterpret_cast<const float4*>(scale + igc + 4);
    float4 sh0 = *reinterpret_cast<const float4*>(shift + igc);
    float4 sh1 = *reinterpret_cast<const float4*>(shift + igc + 4);
#pragma unroll
    for (int j = 0; j < 4; ++j) {
      int v = t + 256 * j;
      int r = v >> 4;
      int grow = rowBase + r;
      ushort4 o0 = make_ushort4(0, 0, 0, 0), o1 = make_ushort4(0, 0, 0, 0);
      if (grow < N) {
        float4 a = *reinterpret_cast<const float4*>(Hin + (size_t)grow * 128 + igc);
        float4 b = *reinterpret_cast<const float4*>(Hin + (size_t)grow * 128 + igc + 4);
        o0.x = f2bf(fmaxf(a.x * sc0.x + sh0.x, 0.f));
        o0.y = f2bf(fmaxf(a.y * sc0.y + sh0.y, 0.f));
        o0.z = f2bf(fmaxf(a.z * sc0.z + sh0.z, 0.f));
        o0.w = f2bf(fmaxf(a.w * sc0.w + sh0.w, 0.f));
        o1.x = f2bf(fmaxf(b.x * sc1.x + sh1.x, 0.f));
        o1.y = f2bf(fmaxf(b.y * sc1.y + sh1.y, 0.f));
        o1.z = f2bf(fmaxf(b.z * sc1.z + sh1.z, 0.f));
        o1.w = f2bf(fmaxf(b.w * sc1.w + sh1.w, 0.f));
      }
      *reinterpret_cast<ushort4*>(&xs[r * LDP + igc]) = o0;
      *reinterpret_cast<ushort4*>(&xs[r * LDP + igc + 4]) = o1;
    }
  } else {
#pragma unroll
    for (int j = 0; j < 4; ++j) {
      int v = t + 256 * j;
      int r = v >> 4;
      int grow = rowBase + r;
      uint4 val = make_uint4(0u, 0u, 0u, 0u);
      if (grow < N) val = *reinterpret_cast<const uint4*>(X + (size_t)grow * 128 + igc);
      *reinterpret_cast<uint4*>(&xs[r * LDP + igc]) = val;
    }
  }
  __syncthreads();

  const int wave = t >> 6;
  const int lane = t & 63;
  const int ln16 = lane & 15;
  const int quad = lane >> 4;
  const int r0 = wave * 16;

  // preload A fragments once (shared across all 4 projections)
  bf16x8 afrag[4];
#pragma unroll
  for (int kk = 0; kk < 4; ++kk)
    afrag[kk] = *reinterpret_cast<const bf16x8*>(&xs[(r0 + ln16) * LDP + kk * 32 + quad * 8]);

  for (int proj = 0; proj < 4; ++proj) {
    const unsigned short* __restrict__ WB = WB4 + proj * 16384;
    const float* __restrict__ bias = go.bias[proj];

    f32x4 acc[8] = {};
#pragma unroll
    for (int kk = 0; kk < 4; ++kk) {
#pragma unroll
      for (int ct = 0; ct < 8; ++ct) {
        bf16x8 b = *reinterpret_cast<const bf16x8*>(WB + ((kk * 8 + ct) * 64 + lane) * 8);
        acc[ct] = __builtin_amdgcn_mfma_f32_16x16x32_bf16(afrag[kk], b, acc[ct], 0, 0, 0);
      }
    }

    const bool asHalf = (proj < 3);
    float* __restrict__ Yf = (float*)go.Y[proj];
    _Float16* __restrict__ Yh = (_Float16*)go.Y[proj];

#pragma unroll
    for (int ct = 0; ct < 8; ++ct) {
      int col = ct * 16 + ln16;
      float bv = bias[col];
#pragma unroll
      for (int reg = 0; reg < 4; ++reg) {
        int grow = rowBase + r0 + quad * 4 + reg;
        if (grow < N) {
          float v = acc[ct][reg] + bv;
          if (asHalf) Yh[(size_t)grow * 128 + col] = (_Float16)v;
          else        Yf[(size_t)grow * 128 + col] = v;
        }
      }
    }
  }
}

// ---------------- fused per-node attention + BN partial stats ----------------
__global__ __launch_bounds__(256) void node_attn(
    const int* __restrict__ rowptr, const int* __restrict__ adj,
    const _Float16* __restrict__ Q, const _Float16* __restrict__ K,
    const _Float16* __restrict__ V, float* __restrict__ H,
    float* __restrict__ Pbuf, int N)
{
  __shared__ float lsum[8][128];
  __shared__ float lsq[8][128];
  int t = threadIdx.x;
  int w = t >> 5, lane = t & 31;
  int n = blockIdx.x * 8 + w;
  bool valid = n < N;
  int nn = valid ? n : 0;
  int p0 = 0, p1 = 0;
  if (valid) { p0 = rowptr[n]; p1 = rowptr[n + 1]; }

  f16x4 qh = *reinterpret_cast<const f16x4*>(Q + (size_t)nn * 128 + lane * 4);
  float4 q = make_float4((float)qh.x, (float)qh.y, (float)qh.z, (float)qh.w);
  float m = -INFINITY, s = 0.f;
  float4 acc = make_float4(0.f, 0.f, 0.f, 0.f);

  int p = p0;
  for (; p + 1 < p1; p += 2) {
    int s0 = adj[p], s1 = adj[p + 1];
    f16x4 k0 = *reinterpret_cast<const f16x4*>(K + (size_t)s0 * 128 + lane * 4);
    f16x4 k1 = *reinterpret_cast<const f16x4*>(K + (size_t)s1 * 128 + lane * 4);
    float d0 = q.x * (float)k0.x + q.y * (float)k0.y + q.z * (float)k0.z + q.w * (float)k0.w;
    float d1 = q.x * (float)k1.x + q.y * (float)k1.y + q.z * (float)k1.z + q.w * (float)k1.w;
#pragma unroll
    for (int off = 16; off; off >>= 1) {
      d0 += __shfl_xor(d0, off, 32);
      d1 += __shfl_xor(d1, off, 32);
    }
    float l0 = d0 * 0.08838834764831845f;
    float l1 = d1 * 0.08838834764831845f;
    float mn = fmaxf(m, fmaxf(l0, l1));
    float sc = __expf(m - mn);
    float w0 = __expf(l0 - mn);
    float w1 = __expf(l1 - mn);
    f16x4 v0 = *reinterpret_cast<const f16x4*>(V + (size_t)s0 * 128 + lane * 4);
    f16x4 v1 = *reinterpret_cast<const f16x4*>(V + (size_t)s1 * 128 + lane * 4);
    acc.x = acc.x * sc + w0 * (float)v0.x + w1 * (float)v1.x;
    acc.y = acc.y * sc + w0 * (float)v0.y + w1 * (float)v1.y;
    acc.z = acc.z * sc + w0 * (float)v0.z + w1 * (float)v1.z;
    acc.w = acc.w * sc + w0 * (float)v0.w + w1 * (float)v1.w;
    s = s * sc + w0 + w1;
    m = mn;
  }
  if (p < p1) {
    int s0 = adj[p];
    f16x4 k0 = *reinterpret_cast<const f16x4*>(K + (size_t)s0 * 128 + lane * 4);
    float d0 = q.x * (float)k0.x + q.y * (float)k0.y + q.z * (float)k0.z + q.w * (float)k0.w;
#pragma unroll
    for (int off = 16; off; off >>= 1) d0 += __shfl_xor(d0, off, 32);
    float l0 = d0 * 0.08838834764831845f;
    float mn = fmaxf(m, l0);
    float sc = __expf(m - mn);
    float w0 = __expf(l0 - mn);
    f16x4 v0 = *reinterpret_cast<const f16x4*>(V + (size_t)s0 * 128 + lane * 4);
    acc.x = acc.x * sc + w0 * (float)v0.x;
    acc.y = acc.y * sc + w0 * (float)v0.y;
    acc.z = acc.z * sc + w0 * (float)v0.z;
    acc.w = acc.w * sc + w0 * (float)v0.w;
    s = s * sc + w0;
    m = mn;
  }

  float4 h = make_float4(0.f, 0.f, 0.f, 0.f);
  if (valid) {
    float inv = 1.0f / (s + 1e-16f);
    h = *reinterpret_cast<const float4*>(H + (size_t)n * 128 + lane * 4);
    h.x += acc.x * inv;
    h.y += acc.y * inv;
    h.z += acc.z * inv;
    h.w += acc.w * inv;
    *reinterpret_cast<float4*>(H + (size_t)n * 128 + lane * 4) = h;
  }

  // BN partial stats over this block's 8 nodes
  *reinterpret_cast<float4*>(&lsum[w][lane * 4]) = h;
  float4 h2 = make_float4(h.x * h.x, h.y * h.y, h.z * h.z, h.w * h.w);
  *reinterpret_cast<float4*>(&lsq[w][lane * 4]) = h2;
  __syncthreads();

  int f = t & 127;
  float a = 0.f;
  if (t < 128) {
#pragma unroll
    for (int n8 = 0; n8 < 8; ++n8) a += lsum[n8][f];
  } else {
#pragma unroll
    for (int n8 = 0; n8 < 8; ++n8) a += lsq[n8][f];
  }
  Pbuf[(size_t)blockIdx.x * 256 + t] = a;
}

// ---------------- BN reduce: 6250x256 partials -> 64x256 -> scale/shift ------
__global__ __launch_bounds__(256) void bn_reduceA(const float* __restrict__ Pbuf,
                                                  float* __restrict__ partial) {
  int t = threadIdx.x;
  float s0 = 0.f, s1 = 0.f, s2 = 0.f, s3 = 0.f;
  int r = blockIdx.x;
  for (; r + 192 < ATTN_BLOCKS; r += 256) {
    s0 += Pbuf[(size_t)(r      ) * 256 + t];
    s1 += Pbuf[(size_t)(r +  64) * 256 + t];
    s2 += Pbuf[(size_t)(r + 128) * 256 + t];
    s3 += Pbuf[(size_t)(r + 192) * 256 + t];
  }
  for (; r < ATTN_BLOCKS; r += 64) s0 += Pbuf[(size_t)r * 256 + t];
  partial[blockIdx.x * 256 + t] = s0 + s1 + s2 + s3;
}

__global__ __launch_bounds__(256) void bn_reduceB(
    const float* __restrict__ partial,
    const float* __restrict__ gamma, const float* __restrict__ beta,
    float* __restrict__ scale, float* __restrict__ shift, int N)
{
  __shared__ float red[256];
  int t = threadIdx.x;
  float s0 = 0.f, s1 = 0.f, s2 = 0.f, s3 = 0.f;
#pragma unroll
  for (int r = 0; r < 64; r += 4) {
    s0 += partial[(r + 0) * 256 + t];
    s1 += partial[(r + 1) * 256 + t];
    s2 += partial[(r + 2) * 256 + t];
    s3 += partial[(r + 3) * 256 + t];
  }
  red[t] = s0 + s1 + s2 + s3;
  __syncthreads();
  if (t < 128) {
    float mean = red[t] / (float)N;
    float var = red[t + 128] / (float)N - mean * mean;
    var = fmaxf(var, 0.f);
    float sc = gamma[t] * rsqrtf(var + 1e-5f);
    scale[t] = sc;
    shift[t] = beta[t] - mean * sc;
  }
}

// ---------------- per-graph pool (BN+ReLU fused) + linear head ---------------
__global__ __launch_bounds__(256) void pool_linear(
    const float* __restrict__ H, const float* __restrict__ scale,
    const float* __restrict__ shift, const int* __restrict__ batch,
    const float* __restrict__ Wlin, const float* __restrict__ blin,
    float* __restrict__ out, int N)
{
  __shared__ float red[256];
  __shared__ float pool[128];
  int g = blockIdx.x;
  int t = threadIdx.x;

  int lo = 0, hi = N;
  while (lo < hi) { int mid = (lo + hi) >> 1; if (batch[mid] < g) lo = mid + 1; else hi = mid; }
  int start = lo;
  hi = N;
  while (lo < hi) { int mid = (lo + hi) >> 1; if (batch[mid] < g + 1) lo = mid + 1; else hi = mid; }
  int end = lo;
  int cnt = end - start;

  int f = t & 127, half = t >> 7;
  float sc = scale[f], sh = shift[f];
  float s = 0.f;
  for (int row = start + half; row < end; row += 2)
    s += fmaxf(H[(size_t)row * 128 + f] * sc + sh, 0.f);
  red[t] = s;
  __syncthreads();
  if (t < 128)
    pool[t] = (red[t] + red[t + 128]) / fmaxf((float)cnt, 1.f);
  __syncthreads();

  if (t < 20) {
    float acc = 0.f;
#pragma unroll 4
    for (int i = 0; i < 128; ++i)
      acc += pool[i] * Wlin[i * 20 + t];
    out[g * 20 + t] = acc + blin[t];
  }
}

// =============================================================================
extern "C" void kernel_launch(void* const* d_in, const int* in_sizes, int n_in,
                              void* d_out, int out_size, void* d_ws, size_t ws_size,
                              hipStream_t stream)
{
  const int N = N_NODES, E = N_EDGES, G = N_GRAPHS;

  const float* x = (const float*)d_in[0];
  const int* ei = (const int*)d_in[1];
  const int* batch = (const int*)d_in[2];
  const float* Wlin = (const float*)d_in[33];
  const float* blin = (const float*)d_in[34];

  char* ws = (char*)d_ws;
  size_t off = 0;
  auto alloc = [&](size_t bytes) -> void* {
    void* p = ws + off;
    off = (off + bytes + 255) & ~(size_t)255;
    return p;
  };
  unsigned short* WB = (unsigned short*)alloc(12 * 16384 * sizeof(unsigned short));
  _Float16* Qh  = (_Float16*)alloc((size_t)N * 128 * 2);
  _Float16* Kh  = (_Float16*)alloc((size_t)N * 128 * 2);
  _Float16* Vh  = (_Float16*)alloc((size_t)N * 128 * 2);
  float* H      = (float*)alloc((size_t)N * 128 * 4);
  int* deg      = (int*)alloc((size_t)N * 4);
  int* rowptr   = (int*)alloc((size_t)(N + 1) * 4);
  int* cursor   = (int*)alloc((size_t)N * 4);
  int* adj      = (int*)alloc((size_t)E * 4);
  int* partials = (int*)alloc((size_t)N_CHUNKS * 4);
  float* Pbuf   = (float*)alloc((size_t)ATTN_BLOCKS * 256 * 4);
  float* bnpart = (float*)alloc((size_t)64 * 256 * 4);
  float* scale  = (float*)alloc(128 * 4);
  float* shift  = (float*)alloc(128 * 4);
  unsigned short* Xb = (unsigned short*)alloc((size_t)N * 128 * 2);

  // ---- one-time per launch: weight repack, x->bf16, CSR build ----
  WPtrs wp;
  for (int L = 0; L < 3; ++L) {
    wp.w[L * 4 + 0] = (const float*)d_in[3 + L * 10 + 0];  // Wq
    wp.w[L * 4 + 1] = (const float*)d_in[3 + L * 10 + 2];  // Wk
    wp.w[L * 4 + 2] = (const float*)d_in[3 + L * 10 + 4];  // Wv
    wp.w[L * 4 + 3] = (const float*)d_in[3 + L * 10 + 6];  // Ws
  }
  repack_kernel<<<dim3(64, 12), 256, 0, stream>>>(wp, WB);
  f32_to_bf16<<<(N * 128 / 4 + 255) / 256, 256, 0, stream>>>(x, Xb, N * 128 / 4);

  hipMemsetAsync(deg, 0, (size_t)N * 4, stream);
  deg_count<<<(E + 255) / 256, 256, 0, stream>>>(ei, deg, E);
  scan_sum<<<N_CHUNKS, 256, 0, stream>>>(deg, partials, N);
  scan_partials<<<1, 128, 0, stream>>>(partials);
  scan_apply<<<N_CHUNKS, 256, 0, stream>>>(deg, partials, rowptr, cursor, N, E);
  csr_scatter<<<(E + 255) / 256, 256, 0, stream>>>(ei, cursor, adj, E);

  for (int L = 0; L < 3; ++L) {
    GemmOut go;
    go.Y[0] = Qh; go.Y[1] = Kh; go.Y[2] = Vh; go.Y[3] = H;
    go.bias[0] = (const float*)d_in[3 + L * 10 + 1];
    go.bias[1] = (const float*)d_in[3 + L * 10 + 3];
    go.bias[2] = (const float*)d_in[3 + L * 10 + 5];
    go.bias[3] = (const float*)d_in[3 + L * 10 + 7];
    gemm_proj<<<(N + 63) / 64, 256, 0, stream>>>(
        Xb, H, scale, shift, WB + L * 4 * 16384, go, (L > 0) ? 1 : 0, N);

    node_attn<<<ATTN_BLOCKS, 256, 0, stream>>>(rowptr, adj, Qh, Kh, Vh, H, Pbuf, N);

    bn_reduceA<<<64, 256, 0, stream>>>(Pbuf, bnpart);
    bn_reduceB<<<1, 256, 0, stream>>>(bnpart,
        (const float*)d_in[3 + L * 10 + 8],
        (const float*)d_in[3 + L * 10 + 9],
        scale, shift, N);

    if (L == 2) {
      pool_linear<<<G, 256, 0, stream>>>(H, scale, shift, batch, Wlin, blin,
                                         (float*)d_out, N);
    }
  }
}

// Round 11
// 479.654 us; speedup vs baseline: 1.3597x; 1.0355x over previous
//
#include <hip/hip_runtime.h>

#define N_NODES 50000
#define N_EDGES 400000
#define DH 128
#define N_GRAPHS 256

#define SCAN_CHUNK 512
#define N_CHUNKS ((N_NODES + SCAN_CHUNK - 1) / SCAN_CHUNK)   // 98
#define ATTN_BLOCKS ((N_NODES + 7) / 8)                      // 6250
#define POOL_CHUNKS ((N_NODES + 63) / 64)                    // 782

typedef __bf16 bf16x8 __attribute__((ext_vector_type(8)));
typedef float f32x4 __attribute__((ext_vector_type(4)));
typedef _Float16 f16x4 __attribute__((ext_vector_type(4)));
typedef _Float16 f16x8 __attribute__((ext_vector_type(8)));

#define DEV __device__ __forceinline__

DEV unsigned short f2bf(float f) {
  union { float f; unsigned int i; } v; v.f = f;
  unsigned int x = v.i;
  unsigned int r = (x + 0x7fffu + ((x >> 16) & 1u)) >> 16;
  return (unsigned short)r;
}

// ---- weight repack into MFMA B-fragment order ------------------------------
struct WPtrs { const float* w[12]; };

__global__ void repack_kernel(WPtrs wp, unsigned short* __restrict__ WB) {
  int mat = blockIdx.y;
  int m = blockIdx.x * 256 + threadIdx.x;   // 0..16383
  int j = m & 7;
  int lane = (m >> 3) & 63;
  int ct = (m >> 9) & 7;
  int kk = m >> 12;
  int i = kk * 32 + (lane >> 4) * 8 + j;
  int o = ct * 16 + (lane & 15);
  WB[mat * 16384 + m] = f2bf(wp.w[mat][i * 128 + o]);
}

// ---------------- fp32 -> bf16 convert (layer-0 x) ---------------------------
__global__ void f32_to_bf16(const float* __restrict__ in, unsigned short* __restrict__ out,
                            int total4) {
  int i = blockIdx.x * 256 + threadIdx.x;
  if (i >= total4) return;
  float4 v = *reinterpret_cast<const float4*>(in + i * 4);
  ushort4 o;
  o.x = f2bf(v.x); o.y = f2bf(v.y); o.z = f2bf(v.z); o.w = f2bf(v.w);
  *reinterpret_cast<ushort4*>(out + i * 4) = o;
}

// ---------------- CSR build --------------------------------------------------
__global__ void deg_count(const int* __restrict__ ei, int* __restrict__ deg, int E) {
  int e = blockIdx.x * 256 + threadIdx.x;
  if (e < E) atomicAdd(&deg[ei[E + e]], 1);
}

__global__ __launch_bounds__(256) void scan_sum(const int* __restrict__ deg,
                                                int* __restrict__ partials, int N) {
  __shared__ int red[256];
  int b = blockIdx.x, t = threadIdx.x;
  int base = b * SCAN_CHUNK + t * 2;
  int s = 0;
  if (base + 1 < N) { int2 v = *reinterpret_cast<const int2*>(deg + base); s = v.x + v.y; }
  else if (base < N) s = deg[base];
  red[t] = s;
  __syncthreads();
  for (int off = 128; off; off >>= 1) {
    if (t < off) red[t] += red[t + off];
    __syncthreads();
  }
  if (t == 0) partials[b] = red[0];
}

__global__ __launch_bounds__(128) void scan_partials(int* __restrict__ partials) {
  __shared__ int s[128];
  int t = threadIdx.x;
  int v = (t < N_CHUNKS) ? partials[t] : 0;
  s[t] = v;
  __syncthreads();
  for (int off = 1; off < 128; off <<= 1) {
    int o = (t >= off) ? s[t - off] : 0;
    __syncthreads();
    s[t] += o;
    __syncthreads();
  }
  if (t < N_CHUNKS) partials[t] = s[t] - v;   // exclusive
}

__global__ __launch_bounds__(256) void scan_apply(const int* __restrict__ deg,
                                                  const int* __restrict__ partials,
                                                  int* __restrict__ rowptr,
                                                  int* __restrict__ cursor, int N, int E) {
  __shared__ int s[256];
  int b = blockIdx.x, t = threadIdx.x;
  int base = b * SCAN_CHUNK + t * 2;
  int d0 = 0, d1 = 0;
  if (base + 1 < N) { int2 v = *reinterpret_cast<const int2*>(deg + base); d0 = v.x; d1 = v.y; }
  else if (base < N) d0 = deg[base];
  int local = d0 + d1;
  s[t] = local;
  __syncthreads();
  for (int off = 1; off < 256; off <<= 1) {
    int o = (t >= off) ? s[t - off] : 0;
    __syncthreads();
    s[t] += o;
    __syncthreads();
  }
  int offp = partials[b] + s[t] - local;
  if (base < N)     { rowptr[base] = offp;          cursor[base] = offp; }
  if (base + 1 < N) { rowptr[base + 1] = offp + d0; cursor[base + 1] = offp + d0; }
  if (b == 0 && t == 0) rowptr[N] = E;
}

__global__ void csr_scatter(const int* __restrict__ ei, int* __restrict__ cursor,
                            int* __restrict__ adj, int E) {
  int e = blockIdx.x * 256 + threadIdx.x;
  if (e < E) {
    int dst = ei[E + e];
    int pos = atomicAdd(&cursor[dst], 1);
    adj[pos] = ei[e];
  }
}

// ---------------- fused 4-projection GEMM: {Q,K,V,H} = BN(X) @ W_p + b_p -----
// All outputs fp16. One block stages its 64-row X tile once; 4 projections.
struct GemmOut { _Float16* Y[4]; const float* bias[4]; };

#define LDP 136   // padded LDS row stride (bf16 elems)

__global__ __launch_bounds__(256) void gemm_proj(
    const unsigned short* __restrict__ X,
    const _Float16* __restrict__ Hin,
    const float* __restrict__ scale, const float* __restrict__ shift,
    const unsigned short* __restrict__ WB4,   // fragment-ordered, 4 mats x 16384
    GemmOut go, int useBN, int N)
{
  __shared__ __align__(16) unsigned short xs[64 * LDP];

  const int t = threadIdx.x;
  const int rowBase = blockIdx.x * 64;
  const int igc = (t & 15) * 8;

  if (useBN) {
    float4 sc0 = *reinterpret_cast<const float4*>(scale + igc);
    float4 sc1 = *reinterpret_cast<const float4*>(scale + igc + 4);
    float4 sh0 = *reinterpret_cast<const float4*>(shift + igc);
    float4 sh1 = *reinterpret_cast<const float4*>(shift + igc + 4);
#pragma unroll
    for (int j = 0; j < 4; ++j) {
      int v = t + 256 * j;
      int r = v >> 4;
      int grow = rowBase + r;
      ushort4 o0 = make_ushort4(0, 0, 0, 0), o1 = make_ushort4(0, 0, 0, 0);
      if (grow < N) {
        f16x8 hv = *reinterpret_cast<const f16x8*>(Hin + (size_t)grow * 128 + igc);
        o0.x = f2bf(fmaxf((float)hv[0] * sc0.x + sh0.x, 0.f));
        o0.y = f2bf(fmaxf((float)hv[1] * sc0.y + sh0.y, 0.f));
        o0.z = f2bf(fmaxf((float)hv[2] * sc0.z + sh0.z, 0.f));
        o0.w = f2bf(fmaxf((float)hv[3] * sc0.w + sh0.w, 0.f));
        o1.x = f2bf(fmaxf((float)hv[4] * sc1.x + sh1.x, 0.f));
        o1.y = f2bf(fmaxf((float)hv[5] * sc1.y + sh1.y, 0.f));
        o1.z = f2bf(fmaxf((float)hv[6] * sc1.z + sh1.z, 0.f));
        o1.w = f2bf(fmaxf((float)hv[7] * sc1.w + sh1.w, 0.f));
      }
      *reinterpret_cast<ushort4*>(&xs[r * LDP + igc]) = o0;
      *reinterpret_cast<ushort4*>(&xs[r * LDP + igc + 4]) = o1;
    }
  } else {
#pragma unroll
    for (int j = 0; j < 4; ++j) {
      int v = t + 256 * j;
      int r = v >> 4;
      int grow = rowBase + r;
      uint4 val = make_uint4(0u, 0u, 0u, 0u);
      if (grow < N) val = *reinterpret_cast<const uint4*>(X + (size_t)grow * 128 + igc);
      *reinterpret_cast<uint4*>(&xs[r * LDP + igc]) = val;
    }
  }
  __syncthreads();

  const int wave = t >> 6;
  const int lane = t & 63;
  const int ln16 = lane & 15;
  const int quad = lane >> 4;
  const int r0 = wave * 16;

  bf16x8 afrag[4];
#pragma unroll
  for (int kk = 0; kk < 4; ++kk)
    afrag[kk] = *reinterpret_cast<const bf16x8*>(&xs[(r0 + ln16) * LDP + kk * 32 + quad * 8]);

  for (int proj = 0; proj < 4; ++proj) {
    const unsigned short* __restrict__ WB = WB4 + proj * 16384;
    const float* __restrict__ bias = go.bias[proj];

    f32x4 acc[8] = {};
#pragma unroll
    for (int kk = 0; kk < 4; ++kk) {
#pragma unroll
      for (int ct = 0; ct < 8; ++ct) {
        bf16x8 b = *reinterpret_cast<const bf16x8*>(WB + ((kk * 8 + ct) * 64 + lane) * 8);
        acc[ct] = __builtin_amdgcn_mfma_f32_16x16x32_bf16(afrag[kk], b, acc[ct], 0, 0, 0);
      }
    }

    _Float16* __restrict__ Yh = go.Y[proj];
#pragma unroll
    for (int ct = 0; ct < 8; ++ct) {
      int col = ct * 16 + ln16;
      float bv = bias[col];
#pragma unroll
      for (int reg = 0; reg < 4; ++reg) {
        int grow = rowBase + r0 + quad * 4 + reg;
        if (grow < N) Yh[(size_t)grow * 128 + col] = (_Float16)(acc[ct][reg] + bv);
      }
    }
  }
}

// ---------------- fused per-node attention + BN partial stats ----------------
// H fp16 read-modify-write; BN partials computed from fp32 register values.
__global__ __launch_bounds__(256) void node_attn(
    const int* __restrict__ rowptr, const int* __restrict__ adj,
    const _Float16* __restrict__ Q, const _Float16* __restrict__ K,
    const _Float16* __restrict__ V, _Float16* __restrict__ H,
    float* __restrict__ Pbuf, int N)
{
  __shared__ float lsum[8][128];
  __shared__ float lsq[8][128];
  int t = threadIdx.x;
  int w = t >> 5, lane = t & 31;
  int n = blockIdx.x * 8 + w;
  bool valid = n < N;
  int nn = valid ? n : 0;
  int p0 = 0, p1 = 0;
  if (valid) { p0 = rowptr[n]; p1 = rowptr[n + 1]; }

  f16x4 qh = *reinterpret_cast<const f16x4*>(Q + (size_t)nn * 128 + lane * 4);
  float4 q = make_float4((float)qh.x, (float)qh.y, (float)qh.z, (float)qh.w);
  float m = -INFINITY, s = 0.f;
  float4 acc = make_float4(0.f, 0.f, 0.f, 0.f);

  int p = p0;
  for (; p + 1 < p1; p += 2) {
    int s0 = adj[p], s1 = adj[p + 1];
    f16x4 k0 = *reinterpret_cast<const f16x4*>(K + (size_t)s0 * 128 + lane * 4);
    f16x4 k1 = *reinterpret_cast<const f16x4*>(K + (size_t)s1 * 128 + lane * 4);
    float d0 = q.x * (float)k0.x + q.y * (float)k0.y + q.z * (float)k0.z + q.w * (float)k0.w;
    float d1 = q.x * (float)k1.x + q.y * (float)k1.y + q.z * (float)k1.z + q.w * (float)k1.w;
#pragma unroll
    for (int off = 16; off; off >>= 1) {
      d0 += __shfl_xor(d0, off, 32);
      d1 += __shfl_xor(d1, off, 32);
    }
    float l0 = d0 * 0.08838834764831845f;
    float l1 = d1 * 0.08838834764831845f;
    float mn = fmaxf(m, fmaxf(l0, l1));
    float sc = __expf(m - mn);
    float w0 = __expf(l0 - mn);
    float w1 = __expf(l1 - mn);
    f16x4 v0 = *reinterpret_cast<const f16x4*>(V + (size_t)s0 * 128 + lane * 4);
    f16x4 v1 = *reinterpret_cast<const f16x4*>(V + (size_t)s1 * 128 + lane * 4);
    acc.x = acc.x * sc + w0 * (float)v0.x + w1 * (float)v1.x;
    acc.y = acc.y * sc + w0 * (float)v0.y + w1 * (float)v1.y;
    acc.z = acc.z * sc + w0 * (float)v0.z + w1 * (float)v1.z;
    acc.w = acc.w * sc + w0 * (float)v0.w + w1 * (float)v1.w;
    s = s * sc + w0 + w1;
    m = mn;
  }
  if (p < p1) {
    int s0 = adj[p];
    f16x4 k0 = *reinterpret_cast<const f16x4*>(K + (size_t)s0 * 128 + lane * 4);
    float d0 = q.x * (float)k0.x + q.y * (float)k0.y + q.z * (float)k0.z + q.w * (float)k0.w;
#pragma unroll
    for (int off = 16; off; off >>= 1) d0 += __shfl_xor(d0, off, 32);
    float l0 = d0 * 0.08838834764831845f;
    float mn = fmaxf(m, l0);
    float sc = __expf(m - mn);
    float w0 = __expf(l0 - mn);
    f16x4 v0 = *reinterpret_cast<const f16x4*>(V + (size_t)s0 * 128 + lane * 4);
    acc.x = acc.x * sc + w0 * (float)v0.x;
    acc.y = acc.y * sc + w0 * (float)v0.y;
    acc.z = acc.z * sc + w0 * (float)v0.z;
    acc.w = acc.w * sc + w0 * (float)v0.w;
    s = s * sc + w0;
    m = mn;
  }

  float4 h = make_float4(0.f, 0.f, 0.f, 0.f);
  if (valid) {
    float inv = 1.0f / (s + 1e-16f);
    f16x4 hh = *reinterpret_cast<const f16x4*>(H + (size_t)n * 128 + lane * 4);
    h.x = (float)hh.x + acc.x * inv;
    h.y = (float)hh.y + acc.y * inv;
    h.z = (float)hh.z + acc.z * inv;
    h.w = (float)hh.w + acc.w * inv;
    f16x4 ho;
    ho.x = (_Float16)h.x; ho.y = (_Float16)h.y; ho.z = (_Float16)h.z; ho.w = (_Float16)h.w;
    *reinterpret_cast<f16x4*>(H + (size_t)n * 128 + lane * 4) = ho;
  }

  *reinterpret_cast<float4*>(&lsum[w][lane * 4]) = h;
  float4 h2 = make_float4(h.x * h.x, h.y * h.y, h.z * h.z, h.w * h.w);
  *reinterpret_cast<float4*>(&lsq[w][lane * 4]) = h2;
  __syncthreads();

  int f = t & 127;
  float a = 0.f;
  if (t < 128) {
#pragma unroll
    for (int n8 = 0; n8 < 8; ++n8) a += lsum[n8][f];
  } else {
#pragma unroll
    for (int n8 = 0; n8 < 8; ++n8) a += lsq[n8][f];
  }
  Pbuf[(size_t)blockIdx.x * 256 + t] = a;
}

// ---------------- BN reduce: 6250x256 partials -> 64x256 -> scale/shift ------
__global__ __launch_bounds__(256) void bn_reduceA(const float* __restrict__ Pbuf,
                                                  float* __restrict__ partial) {
  int t = threadIdx.x;
  float s0 = 0.f, s1 = 0.f, s2 = 0.f, s3 = 0.f;
  int r = blockIdx.x;
  for (; r + 192 < ATTN_BLOCKS; r += 256) {
    s0 += Pbuf[(size_t)(r      ) * 256 + t];
    s1 += Pbuf[(size_t)(r +  64) * 256 + t];
    s2 += Pbuf[(size_t)(r + 128) * 256 + t];
    s3 += Pbuf[(size_t)(r + 192) * 256 + t];
  }
  for (; r < ATTN_BLOCKS; r += 64) s0 += Pbuf[(size_t)r * 256 + t];
  partial[blockIdx.x * 256 + t] = s0 + s1 + s2 + s3;
}

__global__ __launch_bounds__(256) void bn_reduceB(
    const float* __restrict__ partial,
    const float* __restrict__ gamma, const float* __restrict__ beta,
    float* __restrict__ scale, float* __restrict__ shift, int N)
{
  __shared__ float red[256];
  int t = threadIdx.x;
  float s0 = 0.f, s1 = 0.f, s2 = 0.f, s3 = 0.f;
#pragma unroll
  for (int r = 0; r < 64; r += 4) {
    s0 += partial[(r + 0) * 256 + t];
    s1 += partial[(r + 1) * 256 + t];
    s2 += partial[(r + 2) * 256 + t];
    s3 += partial[(r + 3) * 256 + t];
  }
  red[t] = s0 + s1 + s2 + s3;
  __syncthreads();
  if (t < 128) {
    float mean = red[t] / (float)N;
    float var = red[t + 128] / (float)N - mean * mean;
    var = fmaxf(var, 0.f);
    float sc = gamma[t] * rsqrtf(var + 1e-5f);
    scale[t] = sc;
    shift[t] = beta[t] - mean * sc;
  }
}

// ---------------- parallel pool: 64-row chunks, flush at graph boundaries ----
__global__ __launch_bounds__(256) void pool_chunk(
    const _Float16* __restrict__ H, const float* __restrict__ scale,
    const float* __restrict__ shift, const int* __restrict__ batch,
    float* __restrict__ pooled, int N)
{
  int f = threadIdx.x & 127, half = threadIdx.x >> 7;
  int base = blockIdx.x * 64;
  int lim = min(base + 64, N);
  float sc = scale[f], sh = shift[f];
  int curg = -1; float s = 0.f;
  for (int row = base + half; row < lim; row += 2) {
    int g = batch[row];
    if (g != curg) {
      if (curg >= 0) unsafeAtomicAdd(pooled + curg * 128 + f, s);
      curg = g; s = 0.f;
    }
    s += fmaxf((float)H[(size_t)row * 128 + f] * sc + sh, 0.f);
  }
  if (curg >= 0) unsafeAtomicAdd(pooled + curg * 128 + f, s);
}

// ---------------- final linear: out[g,c] = (pooled[g]/cnt[g]) @ Wlin + blin --
__global__ __launch_bounds__(64) void final_linear(
    const float* __restrict__ pooled, const int* __restrict__ batch,
    const float* __restrict__ Wlin, const float* __restrict__ blin,
    float* __restrict__ out, int N)
{
  int g = blockIdx.x;
  int c = threadIdx.x;
  int lo = 0, hi = N;
  while (lo < hi) { int mid = (lo + hi) >> 1; if (batch[mid] < g) lo = mid + 1; else hi = mid; }
  int start = lo;
  hi = N;
  while (lo < hi) { int mid = (lo + hi) >> 1; if (batch[mid] < g + 1) lo = mid + 1; else hi = mid; }
  float inv = 1.0f / fmaxf((float)(lo - start), 1.f);
  if (c < 20) {
    float acc = 0.f;
#pragma unroll 4
    for (int i = 0; i < 128; ++i)
      acc += pooled[g * 128 + i] * Wlin[i * 20 + c];
    out[g * 20 + c] = acc * inv + blin[c];
  }
}

// =============================================================================
extern "C" void kernel_launch(void* const* d_in, const int* in_sizes, int n_in,
                              void* d_out, int out_size, void* d_ws, size_t ws_size,
                              hipStream_t stream)
{
  const int N = N_NODES, E = N_EDGES, G = N_GRAPHS;

  const float* x = (const float*)d_in[0];
  const int* ei = (const int*)d_in[1];
  const int* batch = (const int*)d_in[2];
  const float* Wlin = (const float*)d_in[33];
  const float* blin = (const float*)d_in[34];

  char* ws = (char*)d_ws;
  size_t off = 0;
  auto alloc = [&](size_t bytes) -> void* {
    void* p = ws + off;
    off = (off + bytes + 255) & ~(size_t)255;
    return p;
  };
  unsigned short* WB = (unsigned short*)alloc(12 * 16384 * sizeof(unsigned short));
  _Float16* Qh  = (_Float16*)alloc((size_t)N * 128 * 2);
  _Float16* Kh  = (_Float16*)alloc((size_t)N * 128 * 2);
  _Float16* Vh  = (_Float16*)alloc((size_t)N * 128 * 2);
  _Float16* Hh  = (_Float16*)alloc((size_t)N * 128 * 2);
  int* deg      = (int*)alloc((size_t)N * 4);
  int* rowptr   = (int*)alloc((size_t)(N + 1) * 4);
  int* cursor   = (int*)alloc((size_t)N * 4);
  int* adj      = (int*)alloc((size_t)E * 4);
  int* partials = (int*)alloc((size_t)N_CHUNKS * 4);
  float* Pbuf   = (float*)alloc((size_t)ATTN_BLOCKS * 256 * 4);
  float* bnpart = (float*)alloc((size_t)64 * 256 * 4);
  float* scale  = (float*)alloc(128 * 4);
  float* shift  = (float*)alloc(128 * 4);
  float* pooled = (float*)alloc((size_t)G * 128 * 4);
  unsigned short* Xb = (unsigned short*)alloc((size_t)N * 128 * 2);

  // ---- one-time per launch: weight repack, x->bf16, CSR build ----
  WPtrs wp;
  for (int L = 0; L < 3; ++L) {
    wp.w[L * 4 + 0] = (const float*)d_in[3 + L * 10 + 0];  // Wq
    wp.w[L * 4 + 1] = (const float*)d_in[3 + L * 10 + 2];  // Wk
    wp.w[L * 4 + 2] = (const float*)d_in[3 + L * 10 + 4];  // Wv
    wp.w[L * 4 + 3] = (const float*)d_in[3 + L * 10 + 6];  // Ws
  }
  repack_kernel<<<dim3(64, 12), 256, 0, stream>>>(wp, WB);
  f32_to_bf16<<<(N * 128 / 4 + 255) / 256, 256, 0, stream>>>(x, Xb, N * 128 / 4);

  hipMemsetAsync(deg, 0, (size_t)N * 4, stream);
  deg_count<<<(E + 255) / 256, 256, 0, stream>>>(ei, deg, E);
  scan_sum<<<N_CHUNKS, 256, 0, stream>>>(deg, partials, N);
  scan_partials<<<1, 128, 0, stream>>>(partials);
  scan_apply<<<N_CHUNKS, 256, 0, stream>>>(deg, partials, rowptr, cursor, N, E);
  csr_scatter<<<(E + 255) / 256, 256, 0, stream>>>(ei, cursor, adj, E);

  for (int L = 0; L < 3; ++L) {
    GemmOut go;
    go.Y[0] = Qh; go.Y[1] = Kh; go.Y[2] = Vh; go.Y[3] = Hh;
    go.bias[0] = (const float*)d_in[3 + L * 10 + 1];
    go.bias[1] = (const float*)d_in[3 + L * 10 + 3];
    go.bias[2] = (const float*)d_in[3 + L * 10 + 5];
    go.bias[3] = (const float*)d_in[3 + L * 10 + 7];
    gemm_proj<<<(N + 63) / 64, 256, 0, stream>>>(
        Xb, Hh, scale, shift, WB + L * 4 * 16384, go, (L > 0) ? 1 : 0, N);

    node_attn<<<ATTN_BLOCKS, 256, 0, stream>>>(rowptr, adj, Qh, Kh, Vh, Hh, Pbuf, N);

    bn_reduceA<<<64, 256, 0, stream>>>(Pbuf, bnpart);
    bn_reduceB<<<1, 256, 0, stream>>>(bnpart,
        (const float*)d_in[3 + L * 10 + 8],
        (const float*)d_in[3 + L * 10 + 9],
        scale, shift, N);

    if (L == 2) {
      hipMemsetAsync(pooled, 0, (size_t)G * 128 * 4, stream);
      pool_chunk<<<POOL_CHUNKS, 256, 0, stream>>>(Hh, scale, shift, batch, pooled, N);
      final_linear<<<G, 64, 0, stream>>>(pooled, batch, Wlin, blin, (float*)d_out, N);
    }
  }
}

// Round 12
// 446.000 us; speedup vs baseline: 1.4623x; 1.0755x over previous
//
#include <hip/hip_runtime.h>

#define N_NODES 50000
#define N_EDGES 400000
#define DH 128
#define N_GRAPHS 256

#define SCAN_CHUNK 512
#define N_CHUNKS ((N_NODES + SCAN_CHUNK - 1) / SCAN_CHUNK)   // 98
#define ATTN_BLOCKS ((N_NODES + 15) / 16)                    // 3125
#define POOL_CHUNKS ((N_NODES + 63) / 64)                    // 782

typedef __bf16 bf16x8 __attribute__((ext_vector_type(8)));
typedef float f32x4 __attribute__((ext_vector_type(4)));
typedef _Float16 f16x2 __attribute__((ext_vector_type(2)));
typedef _Float16 f16x8 __attribute__((ext_vector_type(8)));

#define DEV __device__ __forceinline__

#if defined(__has_builtin)
#if __has_builtin(__builtin_amdgcn_fdot2)
#define HAS_FDOT2 1
#endif
#endif

DEV float fdot2acc(f16x2 a, f16x2 b, float c) {
#ifdef HAS_FDOT2
  return __builtin_amdgcn_fdot2(a, b, c, false);
#else
  return (float)a.x * (float)b.x + (float)a.y * (float)b.y + c;
#endif
}

DEV unsigned short f2bf(float f) {
  union { float f; unsigned int i; } v; v.f = f;
  unsigned int x = v.i;
  unsigned int r = (x + 0x7fffu + ((x >> 16) & 1u)) >> 16;
  return (unsigned short)r;
}

// ---- weight repack into MFMA B-fragment order ------------------------------
struct WPtrs { const float* w[12]; };

__global__ void repack_kernel(WPtrs wp, unsigned short* __restrict__ WB) {
  int mat = blockIdx.y;
  int m = blockIdx.x * 256 + threadIdx.x;   // 0..16383
  int j = m & 7;
  int lane = (m >> 3) & 63;
  int ct = (m >> 9) & 7;
  int kk = m >> 12;
  int i = kk * 32 + (lane >> 4) * 8 + j;
  int o = ct * 16 + (lane & 15);
  WB[mat * 16384 + m] = f2bf(wp.w[mat][i * 128 + o]);
}

// ---------------- CSR build --------------------------------------------------
__global__ void deg_count(const int* __restrict__ ei, int* __restrict__ deg, int E) {
  int e = blockIdx.x * 256 + threadIdx.x;
  if (e < E) atomicAdd(&deg[ei[E + e]], 1);
}

__global__ __launch_bounds__(256) void scan_sum(const int* __restrict__ deg,
                                                int* __restrict__ partials, int N) {
  __shared__ int red[256];
  int b = blockIdx.x, t = threadIdx.x;
  int base = b * SCAN_CHUNK + t * 2;
  int s = 0;
  if (base + 1 < N) { int2 v = *reinterpret_cast<const int2*>(deg + base); s = v.x + v.y; }
  else if (base < N) s = deg[base];
  red[t] = s;
  __syncthreads();
  for (int off = 128; off; off >>= 1) {
    if (t < off) red[t] += red[t + off];
    __syncthreads();
  }
  if (t == 0) partials[b] = red[0];
}

__global__ __launch_bounds__(128) void scan_partials(int* __restrict__ partials) {
  __shared__ int s[128];
  int t = threadIdx.x;
  int v = (t < N_CHUNKS) ? partials[t] : 0;
  s[t] = v;
  __syncthreads();
  for (int off = 1; off < 128; off <<= 1) {
    int o = (t >= off) ? s[t - off] : 0;
    __syncthreads();
    s[t] += o;
    __syncthreads();
  }
  if (t < N_CHUNKS) partials[t] = s[t] - v;   // exclusive
}

__global__ __launch_bounds__(256) void scan_apply(const int* __restrict__ deg,
                                                  const int* __restrict__ partials,
                                                  int* __restrict__ rowptr,
                                                  int* __restrict__ cursor, int N, int E) {
  __shared__ int s[256];
  int b = blockIdx.x, t = threadIdx.x;
  int base = b * SCAN_CHUNK + t * 2;
  int d0 = 0, d1 = 0;
  if (base + 1 < N) { int2 v = *reinterpret_cast<const int2*>(deg + base); d0 = v.x; d1 = v.y; }
  else if (base < N) d0 = deg[base];
  int local = d0 + d1;
  s[t] = local;
  __syncthreads();
  for (int off = 1; off < 256; off <<= 1) {
    int o = (t >= off) ? s[t - off] : 0;
    __syncthreads();
    s[t] += o;
    __syncthreads();
  }
  int offp = partials[b] + s[t] - local;
  if (base < N)     { rowptr[base] = offp;          cursor[base] = offp; }
  if (base + 1 < N) { rowptr[base + 1] = offp + d0; cursor[base + 1] = offp + d0; }
  if (b == 0 && t == 0) rowptr[N] = E;
}

__global__ void csr_scatter(const int* __restrict__ ei, int* __restrict__ cursor,
                            int* __restrict__ adj, int E) {
  int e = blockIdx.x * 256 + threadIdx.x;
  if (e < E) {
    int dst = ei[E + e];
    int pos = atomicAdd(&cursor[dst], 1);
    adj[pos] = ei[e];
  }
}

// ---------------- fused 4-projection GEMM: {Q,K,V,H} = BN(X) @ W_p + b_p -----
// mode 0: stage fp32 x -> bf16.  mode 1: stage fp16 H with BN+ReLU -> bf16.
struct GemmOut { _Float16* Y[4]; const float* bias[4]; };

#define LDP 136   // padded LDS row stride (bf16 elems)

__global__ __launch_bounds__(256) void gemm_proj(
    const float* __restrict__ Xf,
    const _Float16* __restrict__ Hin,
    const float* __restrict__ scale, const float* __restrict__ shift,
    const unsigned short* __restrict__ WB4,   // fragment-ordered, 4 mats x 16384
    GemmOut go, int useBN, int N)
{
  __shared__ __align__(16) unsigned short xs[64 * LDP];

  const int t = threadIdx.x;
  const int rowBase = blockIdx.x * 64;
  const int igc = (t & 15) * 8;

  if (useBN) {
    float4 sc0 = *reinterpret_cast<const float4*>(scale + igc);
    float4 sc1 = *reinterpret_cast<const float4*>(scale + igc + 4);
    float4 sh0 = *reinterpret_cast<const float4*>(shift + igc);
    float4 sh1 = *reinterpret_cast<const float4*>(shift + igc + 4);
#pragma unroll
    for (int j = 0; j < 4; ++j) {
      int v = t + 256 * j;
      int r = v >> 4;
      int grow = rowBase + r;
      ushort4 o0 = make_ushort4(0, 0, 0, 0), o1 = make_ushort4(0, 0, 0, 0);
      if (grow < N) {
        f16x8 hv = *reinterpret_cast<const f16x8*>(Hin + (size_t)grow * 128 + igc);
        o0.x = f2bf(fmaxf((float)hv[0] * sc0.x + sh0.x, 0.f));
        o0.y = f2bf(fmaxf((float)hv[1] * sc0.y + sh0.y, 0.f));
        o0.z = f2bf(fmaxf((float)hv[2] * sc0.z + sh0.z, 0.f));
        o0.w = f2bf(fmaxf((float)hv[3] * sc0.w + sh0.w, 0.f));
        o1.x = f2bf(fmaxf((float)hv[4] * sc1.x + sh1.x, 0.f));
        o1.y = f2bf(fmaxf((float)hv[5] * sc1.y + sh1.y, 0.f));
        o1.z = f2bf(fmaxf((float)hv[6] * sc1.z + sh1.z, 0.f));
        o1.w = f2bf(fmaxf((float)hv[7] * sc1.w + sh1.w, 0.f));
      }
      *reinterpret_cast<ushort4*>(&xs[r * LDP + igc]) = o0;
      *reinterpret_cast<ushort4*>(&xs[r * LDP + igc + 4]) = o1;
    }
  } else {
#pragma unroll
    for (int j = 0; j < 4; ++j) {
      int v = t + 256 * j;
      int r = v >> 4;
      int grow = rowBase + r;
      ushort4 o0 = make_ushort4(0, 0, 0, 0), o1 = make_ushort4(0, 0, 0, 0);
      if (grow < N) {
        float4 a = *reinterpret_cast<const float4*>(Xf + (size_t)grow * 128 + igc);
        float4 b = *reinterpret_cast<const float4*>(Xf + (size_t)grow * 128 + igc + 4);
        o0.x = f2bf(a.x); o0.y = f2bf(a.y); o0.z = f2bf(a.z); o0.w = f2bf(a.w);
        o1.x = f2bf(b.x); o1.y = f2bf(b.y); o1.z = f2bf(b.z); o1.w = f2bf(b.w);
      }
      *reinterpret_cast<ushort4*>(&xs[r * LDP + igc]) = o0;
      *reinterpret_cast<ushort4*>(&xs[r * LDP + igc + 4]) = o1;
    }
  }
  __syncthreads();

  const int wave = t >> 6;
  const int lane = t & 63;
  const int ln16 = lane & 15;
  const int quad = lane >> 4;
  const int r0 = wave * 16;

  bf16x8 afrag[4];
#pragma unroll
  for (int kk = 0; kk < 4; ++kk)
    afrag[kk] = *reinterpret_cast<const bf16x8*>(&xs[(r0 + ln16) * LDP + kk * 32 + quad * 8]);

  for (int proj = 0; proj < 4; ++proj) {
    const unsigned short* __restrict__ WB = WB4 + proj * 16384;
    const float* __restrict__ bias = go.bias[proj];

    f32x4 acc[8] = {};
#pragma unroll
    for (int kk = 0; kk < 4; ++kk) {
#pragma unroll
      for (int ct = 0; ct < 8; ++ct) {
        bf16x8 b = *reinterpret_cast<const bf16x8*>(WB + ((kk * 8 + ct) * 64 + lane) * 8);
        acc[ct] = __builtin_amdgcn_mfma_f32_16x16x32_bf16(afrag[kk], b, acc[ct], 0, 0, 0);
      }
    }

    _Float16* __restrict__ Yh = go.Y[proj];
#pragma unroll
    for (int ct = 0; ct < 8; ++ct) {
      int col = ct * 16 + ln16;
      float bv = bias[col];
#pragma unroll
      for (int reg = 0; reg < 4; ++reg) {
        int grow = rowBase + r0 + quad * 4 + reg;
        if (grow < N) Yh[(size_t)grow * 128 + col] = (_Float16)(acc[ct][reg] + bv);
      }
    }
  }
}

// ---------------- fused per-node attention + BN partial stats ----------------
// 16 lanes per node (f16x8 = 16B/lane), 16 nodes per 256-thread block.
__global__ __launch_bounds__(256) void node_attn(
    const int* __restrict__ rowptr, const int* __restrict__ adj,
    const _Float16* __restrict__ Q, const _Float16* __restrict__ K,
    const _Float16* __restrict__ V, _Float16* __restrict__ H,
    float* __restrict__ Pbuf, int N)
{
  __shared__ float lsum[16][128];
  __shared__ float lsq[16][128];
  int t = threadIdx.x;
  int w = t >> 4, lane = t & 15;
  int n = blockIdx.x * 16 + w;
  bool valid = n < N;
  int nn = valid ? n : 0;
  int p0 = 0, p1 = 0;
  if (valid) { p0 = rowptr[n]; p1 = rowptr[n + 1]; }

  f16x8 qv = *reinterpret_cast<const f16x8*>(Q + (size_t)nn * 128 + lane * 8);
  f16x2 q0 = {qv[0], qv[1]}, q1 = {qv[2], qv[3]}, q2 = {qv[4], qv[5]}, q3 = {qv[6], qv[7]};

  float m = -INFINITY, s = 0.f;
  float acc[8] = {};

  int p = p0;
  for (; p + 1 < p1; p += 2) {
    int s0 = adj[p], s1 = adj[p + 1];
    f16x8 k0 = *reinterpret_cast<const f16x8*>(K + (size_t)s0 * 128 + lane * 8);
    f16x8 k1 = *reinterpret_cast<const f16x8*>(K + (size_t)s1 * 128 + lane * 8);
    float d0 = fdot2acc(q0, (f16x2){k0[0], k0[1]},
               fdot2acc(q1, (f16x2){k0[2], k0[3]},
               fdot2acc(q2, (f16x2){k0[4], k0[5]},
               fdot2acc(q3, (f16x2){k0[6], k0[7]}, 0.f))));
    float d1 = fdot2acc(q0, (f16x2){k1[0], k1[1]},
               fdot2acc(q1, (f16x2){k1[2], k1[3]},
               fdot2acc(q2, (f16x2){k1[4], k1[5]},
               fdot2acc(q3, (f16x2){k1[6], k1[7]}, 0.f))));
#pragma unroll
    for (int off = 8; off; off >>= 1) {
      d0 += __shfl_xor(d0, off, 16);
      d1 += __shfl_xor(d1, off, 16);
    }
    float l0 = d0 * 0.08838834764831845f;
    float l1 = d1 * 0.08838834764831845f;
    float mn = fmaxf(m, fmaxf(l0, l1));
    float sc = __expf(m - mn);
    float w0 = __expf(l0 - mn);
    float w1 = __expf(l1 - mn);
    f16x8 v0 = *reinterpret_cast<const f16x8*>(V + (size_t)s0 * 128 + lane * 8);
    f16x8 v1 = *reinterpret_cast<const f16x8*>(V + (size_t)s1 * 128 + lane * 8);
#pragma unroll
    for (int i = 0; i < 8; ++i)
      acc[i] = acc[i] * sc + w0 * (float)v0[i] + w1 * (float)v1[i];
    s = s * sc + w0 + w1;
    m = mn;
  }
  if (p < p1) {
    int s0 = adj[p];
    f16x8 k0 = *reinterpret_cast<const f16x8*>(K + (size_t)s0 * 128 + lane * 8);
    float d0 = fdot2acc(q0, (f16x2){k0[0], k0[1]},
               fdot2acc(q1, (f16x2){k0[2], k0[3]},
               fdot2acc(q2, (f16x2){k0[4], k0[5]},
               fdot2acc(q3, (f16x2){k0[6], k0[7]}, 0.f))));
#pragma unroll
    for (int off = 8; off; off >>= 1) d0 += __shfl_xor(d0, off, 16);
    float l0 = d0 * 0.08838834764831845f;
    float mn = fmaxf(m, l0);
    float sc = __expf(m - mn);
    float w0 = __expf(l0 - mn);
    f16x8 v0 = *reinterpret_cast<const f16x8*>(V + (size_t)s0 * 128 + lane * 8);
#pragma unroll
    for (int i = 0; i < 8; ++i)
      acc[i] = acc[i] * sc + w0 * (float)v0[i];
    s = s * sc + w0;
    m = mn;
  }

  float h[8];
#pragma unroll
  for (int i = 0; i < 8; ++i) h[i] = 0.f;
  if (valid) {
    float inv = 1.0f / (s + 1e-16f);
    f16x8 hh = *reinterpret_cast<const f16x8*>(H + (size_t)n * 128 + lane * 8);
    f16x8 ho;
#pragma unroll
    for (int i = 0; i < 8; ++i) {
      h[i] = (float)hh[i] + acc[i] * inv;
      ho[i] = (_Float16)h[i];
    }
    *reinterpret_cast<f16x8*>(H + (size_t)n * 128 + lane * 8) = ho;
  }

  // BN partial stats
#pragma unroll
  for (int i = 0; i < 8; i += 4) {
    float4 hv = make_float4(h[i], h[i + 1], h[i + 2], h[i + 3]);
    float4 h2 = make_float4(hv.x * hv.x, hv.y * hv.y, hv.z * hv.z, hv.w * hv.w);
    *reinterpret_cast<float4*>(&lsum[w][lane * 8 + i]) = hv;
    *reinterpret_cast<float4*>(&lsq[w][lane * 8 + i]) = h2;
  }
  __syncthreads();

  int f = t & 127;
  float a = 0.f;
  if (t < 128) {
#pragma unroll
    for (int n16 = 0; n16 < 16; ++n16) a += lsum[n16][f];
  } else {
#pragma unroll
    for (int n16 = 0; n16 < 16; ++n16) a += lsq[n16][f];
  }
  Pbuf[(size_t)blockIdx.x * 256 + t] = a;
}

// ---------------- BN reduce: ATTN_BLOCKS x 256 partials -> 64x256 -> scale/shift
__global__ __launch_bounds__(256) void bn_reduceA(const float* __restrict__ Pbuf,
                                                  float* __restrict__ partial) {
  int t = threadIdx.x;
  float s0 = 0.f, s1 = 0.f, s2 = 0.f, s3 = 0.f;
  int r = blockIdx.x;
  for (; r + 192 < ATTN_BLOCKS; r += 256) {
    s0 += Pbuf[(size_t)(r      ) * 256 + t];
    s1 += Pbuf[(size_t)(r +  64) * 256 + t];
    s2 += Pbuf[(size_t)(r + 128) * 256 + t];
    s3 += Pbuf[(size_t)(r + 192) * 256 + t];
  }
  for (; r < ATTN_BLOCKS; r += 64) s0 += Pbuf[(size_t)r * 256 + t];
  partial[blockIdx.x * 256 + t] = s0 + s1 + s2 + s3;
}

__global__ __launch_bounds__(256) void bn_reduceB(
    const float* __restrict__ partial,
    const float* __restrict__ gamma, const float* __restrict__ beta,
    float* __restrict__ scale, float* __restrict__ shift, int N)
{
  __shared__ float red[256];
  int t = threadIdx.x;
  float s0 = 0.f, s1 = 0.f, s2 = 0.f, s3 = 0.f;
#pragma unroll
  for (int r = 0; r < 64; r += 4) {
    s0 += partial[(r + 0) * 256 + t];
    s1 += partial[(r + 1) * 256 + t];
    s2 += partial[(r + 2) * 256 + t];
    s3 += partial[(r + 3) * 256 + t];
  }
  red[t] = s0 + s1 + s2 + s3;
  __syncthreads();
  if (t < 128) {
    float mean = red[t] / (float)N;
    float var = red[t + 128] / (float)N - mean * mean;
    var = fmaxf(var, 0.f);
    float sc = gamma[t] * rsqrtf(var + 1e-5f);
    scale[t] = sc;
    shift[t] = beta[t] - mean * sc;
  }
}

// ---------------- parallel pool: 64-row chunks, flush at graph boundaries ----
__global__ __launch_bounds__(256) void pool_chunk(
    const _Float16* __restrict__ H, const float* __restrict__ scale,
    const float* __restrict__ shift, const int* __restrict__ batch,
    float* __restrict__ pooled, int N)
{
  int f = threadIdx.x & 127, half = threadIdx.x >> 7;
  int base = blockIdx.x * 64;
  int lim = min(base + 64, N);
  float sc = scale[f], sh = shift[f];
  int curg = -1; float s = 0.f;
  for (int row = base + half; row < lim; row += 2) {
    int g = batch[row];
    if (g != curg) {
      if (curg >= 0) unsafeAtomicAdd(pooled + curg * 128 + f, s);
      curg = g; s = 0.f;
    }
    s += fmaxf((float)H[(size_t)row * 128 + f] * sc + sh, 0.f);
  }
  if (curg >= 0) unsafeAtomicAdd(pooled + curg * 128 + f, s);
}

// ---------------- final linear -----------------------------------------------
__global__ __launch_bounds__(64) void final_linear(
    const float* __restrict__ pooled, const int* __restrict__ batch,
    const float* __restrict__ Wlin, const float* __restrict__ blin,
    float* __restrict__ out, int N)
{
  int g = blockIdx.x;
  int c = threadIdx.x;
  int lo = 0, hi = N;
  while (lo < hi) { int mid = (lo + hi) >> 1; if (batch[mid] < g) lo = mid + 1; else hi = mid; }
  int start = lo;
  hi = N;
  while (lo < hi) { int mid = (lo + hi) >> 1; if (batch[mid] < g + 1) lo = mid + 1; else hi = mid; }
  float inv = 1.0f / fmaxf((float)(lo - start), 1.f);
  if (c < 20) {
    float acc = 0.f;
#pragma unroll 4
    for (int i = 0; i < 128; ++i)
      acc += pooled[g * 128 + i] * Wlin[i * 20 + c];
    out[g * 20 + c] = acc * inv + blin[c];
  }
}

// =============================================================================
extern "C" void kernel_launch(void* const* d_in, const int* in_sizes, int n_in,
                              void* d_out, int out_size, void* d_ws, size_t ws_size,
                              hipStream_t stream)
{
  const int N = N_NODES, E = N_EDGES, G = N_GRAPHS;

  const float* x = (const float*)d_in[0];
  const int* ei = (const int*)d_in[1];
  const int* batch = (const int*)d_in[2];
  const float* Wlin = (const float*)d_in[33];
  const float* blin = (const float*)d_in[34];

  char* ws = (char*)d_ws;
  size_t off = 0;
  auto alloc = [&](size_t bytes) -> void* {
    void* p = ws + off;
    off = (off + bytes + 255) & ~(size_t)255;
    return p;
  };
  unsigned short* WB = (unsigned short*)alloc(12 * 16384 * sizeof(unsigned short));
  _Float16* Qh  = (_Float16*)alloc((size_t)N * 128 * 2);
  _Float16* Kh  = (_Float16*)alloc((size_t)N * 128 * 2);
  _Float16* Vh  = (_Float16*)alloc((size_t)N * 128 * 2);
  _Float16* Hh  = (_Float16*)alloc((size_t)N * 128 * 2);
  int* deg      = (int*)alloc((size_t)N * 4);
  int* rowptr   = (int*)alloc((size_t)(N + 1) * 4);
  int* cursor   = (int*)alloc((size_t)N * 4);
  int* adj      = (int*)alloc((size_t)E * 4);
  int* partials = (int*)alloc((size_t)N_CHUNKS * 4);
  float* Pbuf   = (float*)alloc((size_t)ATTN_BLOCKS * 256 * 4);
  float* bnpart = (float*)alloc((size_t)64 * 256 * 4);
  float* scale  = (float*)alloc(128 * 4);
  float* shift  = (float*)alloc(128 * 4);
  float* pooled = (float*)alloc((size_t)G * 128 * 4);

  // ---- one-time per launch: weight repack, CSR build ----
  WPtrs wp;
  for (int L = 0; L < 3; ++L) {
    wp.w[L * 4 + 0] = (const float*)d_in[3 + L * 10 + 0];  // Wq
    wp.w[L * 4 + 1] = (const float*)d_in[3 + L * 10 + 2];  // Wk
    wp.w[L * 4 + 2] = (const float*)d_in[3 + L * 10 + 4];  // Wv
    wp.w[L * 4 + 3] = (const float*)d_in[3 + L * 10 + 6];  // Ws
  }
  repack_kernel<<<dim3(64, 12), 256, 0, stream>>>(wp, WB);

  hipMemsetAsync(deg, 0, (size_t)N * 4, stream);
  deg_count<<<(E + 255) / 256, 256, 0, stream>>>(ei, deg, E);
  scan_sum<<<N_CHUNKS, 256, 0, stream>>>(deg, partials, N);
  scan_partials<<<1, 128, 0, stream>>>(partials);
  scan_apply<<<N_CHUNKS, 256, 0, stream>>>(deg, partials, rowptr, cursor, N, E);
  csr_scatter<<<(E + 255) / 256, 256, 0, stream>>>(ei, cursor, adj, E);

  for (int L = 0; L < 3; ++L) {
    GemmOut go;
    go.Y[0] = Qh; go.Y[1] = Kh; go.Y[2] = Vh; go.Y[3] = Hh;
    go.bias[0] = (const float*)d_in[3 + L * 10 + 1];
    go.bias[1] = (const float*)d_in[3 + L * 10 + 3];
    go.bias[2] = (const float*)d_in[3 + L * 10 + 5];
    go.bias[3] = (const float*)d_in[3 + L * 10 + 7];
    gemm_proj<<<(N + 63) / 64, 256, 0, stream>>>(
        x, Hh, scale, shift, WB + L * 4 * 16384, go, (L > 0) ? 1 : 0, N);

    node_attn<<<ATTN_BLOCKS, 256, 0, stream>>>(rowptr, adj, Qh, Kh, Vh, Hh, Pbuf, N);

    bn_reduceA<<<64, 256, 0, stream>>>(Pbuf, bnpart);
    bn_reduceB<<<1, 256, 0, stream>>>(bnpart,
        (const float*)d_in[3 + L * 10 + 8],
        (const float*)d_in[3 + L * 10 + 9],
        scale, shift, N);

    if (L == 2) {
      hipMemsetAsync(pooled, 0, (size_t)G * 128 * 4, stream);
      pool_chunk<<<POOL_CHUNKS, 256, 0, stream>>>(Hh, scale, shift, batch, pooled, N);
      final_linear<<<G, 64, 0, stream>>>(pooled, batch, Wlin, blin, (float*)d_out, N);
    }
  }
}